// Round 3
// baseline (1524.225 us; speedup 1.0000x reference)
//
#include <hip/hip_runtime.h>

#define DEVINL __device__ __forceinline__

typedef unsigned short u16;
typedef unsigned int u32;
typedef unsigned char u8;
typedef __attribute__((ext_vector_type(8))) short short8;
typedef __attribute__((ext_vector_type(4))) float f32x4;

// ---------------- numeric helpers ----------------
DEVINL float b2f(u16 u) { union { u32 u; float f; } v; v.u = ((u32)u) << 16; return v.f; }
DEVINL u16 f2b(float f) {
  union { float f; u32 u; } v; v.f = f;
  u32 u = v.u;
  return (u16)((u + 0x7FFFu + ((u >> 16) & 1u)) >> 16);  // RNE
}
DEVINL float sigmoid_f(float x) { float c = fminf(fmaxf(x, -30.f), 30.f); return 1.f / (1.f + __expf(-c)); }
DEVINL float tanh_f(float x) { float c = fminf(fmaxf(x, -15.f), 15.f); float e = __expf(2.f * c); return (e - 1.f) / (e + 1.f); }

// ---------------- dtype detection ----------------
// flags[0]=1 if float inputs are f32 (else packed bf16); flags[1]=1 if mask is bool bytes (else int32)
__global__ void detect_k(const u32* mg, const u32* mask, u32* flags) {
  __shared__ int any8;
  if (threadIdx.x == 0) any8 = 0;
  __syncthreads();
  for (int i = threadIdx.x; i < 4096; i += 256) { if (mask[i] > 1u) any8 = 1; }
  __syncthreads();
  if (threadIdx.x == 0) {
    flags[0] = (mg[0] == 0x3F800000u) ? 1u : 0u;
    flags[1] = any8 ? 1u : 0u;
  }
}

// ---------------- table-driven convert (f32->bf16 or bf16 copy) ----------------
#define NCVT 25
struct CvtTab { const void* src[NCVT]; u16* dst[NCVT]; int n[NCVT]; };

__global__ __launch_bounds__(256) void cvt_table(CvtTab tb, const u32* flags) {
  int e = blockIdx.y;
  int n = tb.n[e];
  int idx = blockIdx.x * 256 + threadIdx.x, step = gridDim.x * 256;
  if (flags[0]) {
    const float* s = (const float*)tb.src[e]; u16* d = tb.dst[e];
    for (int i = idx; i < n; i += step) d[i] = f2b(s[i]);
  } else {
    const u16* s = (const u16*)tb.src[e]; u16* d = tb.dst[e];
    for (int i = idx; i < n; i += step) d[i] = s[i];
  }
}

// ---------------- mask -> u8 (0/1) ----------------
__global__ __launch_bounds__(256) void cvt_mask(const void* src, u32* dst, const u32* flags) {
  size_t i = (size_t)blockIdx.x * 256 + threadIdx.x;  // word index (4 mask elems)
  if (flags[1]) {
    dst[i] = ((const u32*)src)[i];  // bool bytes 0/1: copy
  } else {
    int4 w = ((const int4*)src)[i];
    dst[i] = (w.x ? 1u : 0u) | ((w.y ? 1u : 0u) << 8) | ((w.z ? 1u : 0u) << 16) | ((w.w ? 1u : 0u) << 24);
  }
}

// ---------------- fused convert + transpose (up to 6 square 1024x1024 mats) ----------------
// src[z] is the BASE pointer; soff[z] is the per-slice ELEMENT offset (dtype-independent).
struct TPC { const void* src[6]; u16* dst[6]; long soff[6]; };

__global__ __launch_bounds__(256) void transpose_cvt(TPC p, const u32* flags) {
  __shared__ u16 t[64][65];
  int z = blockIdx.z, tx = threadIdx.x;
  int x0 = blockIdx.x * 64, y0 = blockIdx.y * 64;
  if (flags[0]) {
    const float* s = (const float*)p.src[z] + p.soff[z];
    for (int i = threadIdx.y; i < 64; i += 4) t[i][tx] = f2b(s[(size_t)(y0 + i) * 1024 + x0 + tx]);
  } else {
    const u16* s = (const u16*)p.src[z] + p.soff[z];
    for (int i = threadIdx.y; i < 64; i += 4) t[i][tx] = s[(size_t)(y0 + i) * 1024 + x0 + tx];
  }
  __syncthreads();
  u16* d = p.dst[z];
  for (int i = threadIdx.y; i < 64; i += 4) d[(size_t)(x0 + i) * 1024 + y0 + tx] = t[tx][i];
}

// ---------------- generic 128x128 MFMA GEMM, B given TRANSPOSED ([N][K]) ----------------
struct GemmP {
  const u16* A; const u16* Bt; char* C;
  long sAz, sBz;
  size_t sCzB;
  int lda, ldb, ldc, K;
};
struct Ep {
  const u16 *bias, *bias1, *bias2, *comb, *mgate, *gw;
  const u8* mask8;
  const u32* flags;
  char *cQ, *cK, *cV;
  float scale;
  int accum;
};

template <int MODE>
__global__ __launch_bounds__(256, 2) void gemm_bt(GemmP p, Ep ep) {
  __shared__ u16 As[128 * 32];
  __shared__ u16 Bs[128 * 32];
  const int tid = threadIdx.x;
  const int lane = tid & 63, wave = tid >> 6;
  const int wm = wave >> 1, wn = wave & 1;
  const int z = blockIdx.z;
  const int m0 = blockIdx.y * 128, n0 = blockIdx.x * 128;

  const char* Ab = (const char*)p.A + ((size_t)z * p.sAz + (size_t)m0 * p.lda) * 2;
  const char* Bb = (const char*)p.Bt + ((size_t)z * p.sBz + (size_t)n0 * p.ldb) * 2;

  f32x4 acc[4][4];
  const f32x4 zv = {0.f, 0.f, 0.f, 0.f};
#pragma unroll
  for (int i = 0; i < 4; i++)
#pragma unroll
    for (int j = 0; j < 4; j++) acc[i][j] = zv;

  const int lr = lane & 15;
  const int kg = (lane >> 4) * 8;
  const int ldaB = p.lda * 2, ldbB = p.ldb * 2;

  const int o0 = wave * 2048 + lane * 16;
  const int r0 = o0 >> 6, kb0 = o0 & 63;
  const int o1 = o0 + 1024;
  const int r1 = o1 >> 6, kb1 = o1 & 63;

  for (int k0 = 0; k0 < p.K; k0 += 32) {
    short8 va0 = *(const short8*)(Ab + (size_t)r0 * ldaB + k0 * 2 + kb0);
    short8 va1 = *(const short8*)(Ab + (size_t)r1 * ldaB + k0 * 2 + kb1);
    short8 vb0 = *(const short8*)(Bb + (size_t)r0 * ldbB + k0 * 2 + kb0);
    short8 vb1 = *(const short8*)(Bb + (size_t)r1 * ldbB + k0 * 2 + kb1);
    __syncthreads();
    *(short8*)((char*)As + o0) = va0;
    *(short8*)((char*)As + o1) = va1;
    *(short8*)((char*)Bs + o0) = vb0;
    *(short8*)((char*)Bs + o1) = vb1;
    __syncthreads();
    short8 af[4], bfr[4];
#pragma unroll
    for (int mi = 0; mi < 4; mi++) af[mi] = *(const short8*)&As[(wm * 64 + mi * 16 + lr) * 32 + kg];
#pragma unroll
    for (int ni = 0; ni < 4; ni++) bfr[ni] = *(const short8*)&Bs[(wn * 64 + ni * 16 + lr) * 32 + kg];
#pragma unroll
    for (int mi = 0; mi < 4; mi++)
#pragma unroll
      for (int ni = 0; ni < 4; ni++)
        acc[mi][ni] = __builtin_amdgcn_mfma_f32_16x16x32_bf16(af[mi], bfr[ni], acc[mi][ni], 0, 0, 0);
  }

  char* Cb = p.C + (size_t)z * p.sCzB;
  const int rb = (lane >> 4) << 2;
#pragma unroll
  for (int mi = 0; mi < 4; mi++) {
#pragma unroll
    for (int ni = 0; ni < 4; ni++) {
      const int row0 = m0 + wm * 64 + mi * 16 + rb;
      const int col = n0 + wn * 64 + ni * 16 + lr;
      f32x4 v = acc[mi][ni];
      if constexpr (MODE == 0) {
        float bv = b2f(ep.bias[col]);
        u16* C = (u16*)Cb;
#pragma unroll
        for (int j = 0; j < 4; j++) { float a = v[j] + bv; C[(size_t)(row0 + j) * p.ldc + col] = f2b(a * sigmoid_f(a)); }
      } else if constexpr (MODE == 1) {
        float bv = b2f(ep.bias[col]);
        float w = b2f(ep.gw[0]);
        u16* C = (u16*)Cb;
#pragma unroll
        for (int j = 0; j < 4; j++) {
          size_t idx = (size_t)(row0 + j) * p.ldc + col;
          float t = w * sigmoid_f(v[j] + bv);
          if (ep.accum) t += b2f(C[idx]);
          C[idx] = f2b(t);
        }
      } else if constexpr (MODE == 2) {
        const u16* bp = (z == 0) ? ep.bias : ((z == 1) ? ep.bias1 : ep.bias2);
        float bv = b2f(bp[col]);
        if (z == 0) {
          u16* C = (u16*)ep.cQ;
#pragma unroll
          for (int j = 0; j < 4; j++) C[(size_t)(row0 + j) * p.ldc + col] = f2b(v[j] + bv);
        } else if (z == 1) {
          u16* C = (u16*)ep.cK;
#pragma unroll
          for (int j = 0; j < 4; j++) C[(size_t)(row0 + j) * p.ldc + col] = f2b(v[j] + bv);
        } else {
          int b = row0 >> 10, s = row0 & 1023;
          ushort4 pk;
          pk.x = f2b(v[0] + bv); pk.y = f2b(v[1] + bv); pk.z = f2b(v[2] + bv); pk.w = f2b(v[3] + bv);
          *(ushort4*)((u16*)ep.cV + (size_t)b * 1048576 + (size_t)col * 1024 + s) = pk;
        }
      } else if constexpr (MODE == 3) {
        float* C = (float*)Cb;
        const u8* mrow = ep.mask8 + (size_t)z * 1048576;
#pragma unroll
        for (int j = 0; j < 4; j++) {
          float sc = v[j] * ep.scale;
          C[(size_t)(row0 + j) * p.ldc + col] = mrow[(size_t)(row0 + j) * 1024 + col] ? sc : -1e30f;
        }
      } else if constexpr (MODE == 4) {
        ushort4 pk;
        pk.x = f2b(v[0]); pk.y = f2b(v[1]); pk.z = f2b(v[2]); pk.w = f2b(v[3]);
        *(ushort4*)((u16*)Cb + (size_t)col * 1024 + row0) = pk;
      } else if constexpr (MODE == 5) {
        float bv = b2f(ep.bias[col]);
        float mg = b2f(ep.mgate[col]);
        u16* C = (u16*)Cb;
#pragma unroll
        for (int j = 0; j < 4; j++) {
          size_t idx = (size_t)(row0 + j) * p.ldc + col;
          C[idx] = f2b((v[j] + bv) * b2f(ep.comb[idx]) * mg);
        }
      } else {  // MODE 6
        float bv = b2f(ep.bias[col]);
        if (ep.flags[0]) {
          float* C = (float*)Cb;
#pragma unroll
          for (int j = 0; j < 4; j++) C[(size_t)(row0 + j) * p.ldc + col] = v[j] + bv;
        } else {
          u16* C = (u16*)Cb;
#pragma unroll
          for (int j = 0; j < 4; j++) C[(size_t)(row0 + j) * p.ldc + col] = f2b(v[j] + bv);
        }
      }
    }
  }
}

// ---------------- gated = x * Gsum (in place over Gsum) ----------------
__global__ __launch_bounds__(256) void gate_combine(const u16* x, u16* gs) {
  size_t i = ((size_t)blockIdx.x * 256 + threadIdx.x) * 4;
  ushort4 xv = *(const ushort4*)(x + i);
  ushort4 a = *(const ushort4*)(gs + i);
  ushort4 o;
  o.x = f2b(b2f(xv.x) * b2f(a.x));
  o.y = f2b(b2f(xv.y) * b2f(a.y));
  o.z = f2b(b2f(xv.z) * b2f(a.z));
  o.w = f2b(b2f(xv.w) * b2f(a.w));
  *(ushort4*)(gs + i) = o;
}

// ---------------- column mean over seq ----------------
__global__ __launch_bounds__(256) void colmean(const u16* X, float* Mo) {
  int d = blockIdx.x * 256 + threadIdx.x;
  int b = blockIdx.y;
  const u16* p = X + (size_t)b * 1048576 + d;
  float s = 0.f;
  for (int i = 0; i < 1024; i++) s += b2f(p[(size_t)i * 1024]);
  Mo[b * 1024 + d] = s * (1.f / 1024.f);
}

// ---------------- tiny gate MLP ----------------
__global__ __launch_bounds__(256) void mlp_gate(const float* Mv, const u16* W1, const u16* b1,
                                                const u16* W2, const u16* b2, float* outv, int H) {
  int b = blockIdx.x, t = blockIdx.y, tid = threadIdx.x;
  __shared__ float mv[1024];
  __shared__ float red[256];
  for (int i = tid; i < 1024; i += 256) mv[i] = Mv[b * 1024 + i];
  __syncthreads();
  const u16* W1t = W1 + (size_t)t * 1024 * H;
  float acc = 0.f;
  for (int j = tid; j < H; j += 256) {
    float a = b2f(b1[t * H + j]);
    for (int d = 0; d < 1024; d++) a += mv[d] * b2f(W1t[(size_t)d * H + j]);
    acc += (a * sigmoid_f(a)) * b2f(W2[t * H + j]);
  }
  red[tid] = acc;
  __syncthreads();
  for (int s = 128; s > 0; s >>= 1) { if (tid < s) red[tid] += red[tid + s]; __syncthreads(); }
  if (tid == 0) outv[t * 8 + b] = sigmoid_f(red[0] + b2f(b2[t]));
}

// ---------------- U[t][r][j] = tanh(cf[t][b] * dot(gated[r,:], Bm[t][:,j])) ----------------
__global__ __launch_bounds__(64) void ssm_u(const u16* gated, const u16* Bm, const float* cf, float* U) {
  int r = blockIdx.x, t = blockIdx.y, lane = threadIdx.x;
  int j = lane >> 2, pp = lane & 3;
  const u16* g = gated + (size_t)r * 1024 + pp * 256;
  const u16* bm = Bm + (size_t)t * 16384 + (size_t)pp * 256 * 16 + j;
  float a = 0.f;
  for (int d = 0; d < 256; d++) a += b2f(g[d]) * b2f(bm[(size_t)d * 16]);
  a += __shfl_xor(a, 1);
  a += __shfl_xor(a, 2);
  if (pp == 0) {
    int b = r >> 10;
    U[((size_t)t * 8192 + r) * 16 + j] = tanh_f(cf[t * 8 + b] * a);
  }
}

// ---------------- sequential scan ----------------
__global__ __launch_bounds__(64) void ssm_scan(const u16* Aw, const float* U, float* Ho) {
  int b = blockIdx.x, t = blockIdx.y, lane = threadIdx.x;
  int j = lane & 15;
  float a[16];
#pragma unroll
  for (int k = 0; k < 16; k++) a[k] = b2f(Aw[t * 256 + k * 16 + j]);
  const float* Ur = U + ((size_t)t * 8192 + (size_t)b * 1024) * 16;
  float* Hr = Ho + ((size_t)t * 8192 + (size_t)b * 1024) * 16;
  float h = 0.f;
  for (int s = 0; s < 1024; s++) {
    float x0 = 0.f, x1 = 0.f;
#pragma unroll
    for (int k = 0; k < 16; k += 2) { x0 += __shfl(h, k) * a[k]; x1 += __shfl(h, k + 1) * a[k + 1]; }
    h = tanh_f(x0 + x1) + Ur[(size_t)s * 16 + j];
    if (lane < 16) Hr[(size_t)s * 16 + j] = h;
  }
}

// ---------------- comb = sum_t tw[t]*(tanh(H@C[t]) + Dv[t]*cf*gated) ----------------
__global__ __launch_bounds__(256) void comb_k(const float* Hbuf, const u16* C, const u16* Dv,
                                              const float* cf, const u16* tsl, const u16* gated,
                                              u16* comb) {
  int r = blockIdx.x, tid = threadIdx.x;
  int b = r >> 10;
  __shared__ float Hs[3][16];
  __shared__ float tw[3];
  if (tid < 48) Hs[tid >> 4][tid & 15] = Hbuf[((size_t)(tid >> 4) * 8192 + r) * 16 + (tid & 15)];
  if (tid == 0) {
    float l0 = b2f(tsl[0]), l1 = b2f(tsl[1]), l2 = b2f(tsl[2]);
    float m = fmaxf(l0, fmaxf(l1, l2));
    float e0 = __expf(l0 - m), e1 = __expf(l1 - m), e2 = __expf(l2 - m);
    float s = e0 + e1 + e2;
    tw[0] = e0 / s; tw[1] = e1 / s; tw[2] = e2 / s;
  }
  __syncthreads();
  int d0 = tid * 4;
  ushort4 gv = *(const ushort4*)(gated + (size_t)r * 1024 + d0);
  float g0 = b2f(gv.x), g1 = b2f(gv.y), g2 = b2f(gv.z), g3v = b2f(gv.w);
  float o0 = 0, o1 = 0, o2 = 0, o3 = 0;
#pragma unroll
  for (int t = 0; t < 3; t++) {
    float w = tw[t], cfv = cf[t * 8 + b];
    float dA = 0, dB = 0, dC = 0, dD = 0;
#pragma unroll
    for (int k = 0; k < 16; k++) {
      float h = Hs[t][k];
      ushort4 cv = *(const ushort4*)(C + ((size_t)t * 16 + k) * 1024 + d0);
      dA += h * b2f(cv.x); dB += h * b2f(cv.y); dC += h * b2f(cv.z); dD += h * b2f(cv.w);
    }
    float dvw = w * cfv;
    o0 += w * tanh_f(dA) + dvw * b2f(Dv[t * 1024 + d0 + 0]) * g0;
    o1 += w * tanh_f(dB) + dvw * b2f(Dv[t * 1024 + d0 + 1]) * g1;
    o2 += w * tanh_f(dC) + dvw * b2f(Dv[t * 1024 + d0 + 2]) * g2;
    o3 += w * tanh_f(dD) + dvw * b2f(Dv[t * 1024 + d0 + 3]) * g3v;
  }
  ushort4 ov;
  ov.x = f2b(o0); ov.y = f2b(o1); ov.z = f2b(o2); ov.w = f2b(o3);
  *(ushort4*)(comb + (size_t)r * 1024 + d0) = ov;
}

// ---------------- row softmax, IN PLACE: f32 row -> bf16 in low half ----------------
__global__ __launch_bounds__(256) void softmax_row(float* S) {
  int r = blockIdx.x, tid = threadIdx.x;
  float* row = S + (size_t)r * 1024;
  float4 v = ((const float4*)row)[tid];
  float mx = fmaxf(fmaxf(v.x, v.y), fmaxf(v.z, v.w));
  for (int o = 32; o; o >>= 1) mx = fmaxf(mx, __shfl_xor(mx, o));
  __shared__ float sm[4], ssum[4];
  int ln = tid & 63, wv = tid >> 6;
  if (!ln) sm[wv] = mx;
  __syncthreads();
  mx = fmaxf(fmaxf(sm[0], sm[1]), fmaxf(sm[2], sm[3]));
  float e0 = __expf(v.x - mx), e1 = __expf(v.y - mx), e2 = __expf(v.z - mx), e3 = __expf(v.w - mx);
  float s = e0 + e1 + e2 + e3;
  for (int o = 32; o; o >>= 1) s += __shfl_xor(s, o);
  if (!ln) ssum[wv] = s;
  __syncthreads();
  s = ssum[0] + ssum[1] + ssum[2] + ssum[3];
  float inv = 1.f / s;
  ushort4 pk;
  pk.x = f2b(e0 * inv); pk.y = f2b(e1 * inv); pk.z = f2b(e2 * inv); pk.w = f2b(e3 * inv);
  __syncthreads();
  ((ushort4*)row)[tid] = pk;
}

// ---------------- comp = mem_gated*cpf ; layernorm ----------------
__global__ __launch_bounds__(256) void ln_k(const u16* MG, const float* cpf, const u16* lng,
                                            const u16* lnb, u16* outp) {
  int r = blockIdx.x, tid = threadIdx.x;
  float cfv = cpf[r >> 10];
  ushort4 m4 = *(const ushort4*)(MG + (size_t)r * 1024 + tid * 4);
  float c0 = b2f(m4.x) * cfv, c1 = b2f(m4.y) * cfv, c2 = b2f(m4.z) * cfv, c3 = b2f(m4.w) * cfv;
  float s = c0 + c1 + c2 + c3;
  float q = c0 * c0 + c1 * c1 + c2 * c2 + c3 * c3;
  int ln = tid & 63, wv = tid >> 6;
  for (int o = 32; o; o >>= 1) { s += __shfl_xor(s, o); q += __shfl_xor(q, o); }
  __shared__ float ss[4], qq[4];
  if (!ln) { ss[wv] = s; qq[wv] = q; }
  __syncthreads();
  s = ss[0] + ss[1] + ss[2] + ss[3];
  q = qq[0] + qq[1] + qq[2] + qq[3];
  float mu = s * (1.f / 1024.f);
  float var = q * (1.f / 1024.f) - mu * mu;
  float inv = rsqrtf(fmaxf(var, 0.f) + 1e-5f);
  int d = tid * 4;
  ushort4 ov;
  ov.x = f2b((c0 - mu) * inv * b2f(lng[d + 0]) + b2f(lnb[d + 0]));
  ov.y = f2b((c1 - mu) * inv * b2f(lng[d + 1]) + b2f(lnb[d + 1]));
  ov.z = f2b((c2 - mu) * inv * b2f(lng[d + 2]) + b2f(lnb[d + 2]));
  ov.w = f2b((c3 - mu) * inv * b2f(lng[d + 3]) + b2f(lnb[d + 3]));
  *(ushort4*)(outp + (size_t)r * 1024 + d) = ov;
}

// =================================================================================
extern "C" void kernel_launch(void* const* d_in, const int* in_sizes, int n_in,
                              void* d_out, int out_size, void* d_ws, size_t ws_size,
                              hipStream_t stream) {
  (void)in_sizes; (void)n_in; (void)out_size; (void)ws_size;
  const void* x = d_in[0];
  const void* mask = d_in[1];
  const void* tsl = d_in[2];
  const void* gw1 = d_in[3];
  const void* gb1 = d_in[4];
  const void* gw2 = d_in[5];
  const void* gb2 = d_in[6];
  const void* gwts = d_in[7];
  const void* ssmA = d_in[8];
  const void* ssmBm = d_in[9];
  const void* ssmC = d_in[10];
  const void* ssmD = d_in[11];
  const void* cgw1 = d_in[12];
  const void* cgb1 = d_in[13];
  const void* cgw2 = d_in[14];
  const void* cgb2 = d_in[15];
  const void* wq = d_in[16]; const void* bq = d_in[17];
  const void* wk = d_in[18]; const void* bk = d_in[19];
  const void* wv = d_in[20]; const void* bvp = d_in[21];
  const void* wo = d_in[22]; const void* bo = d_in[23];
  const void* mgate = d_in[24];
  const void* cpw1 = d_in[25];
  const void* cpb1 = d_in[26];
  const void* cpw2 = d_in[27];
  const void* cpb2 = d_in[28];
  const void* lng = d_in[29];
  const void* lnb = d_in[30];
  const void* outw = d_in[31];
  const void* outb = d_in[32];

  // ---- workspace layout ----
  char* ws = (char*)d_ws;
  const size_t MBe = 1048576;
  u16* W = (u16*)ws;                       // 6 x 2MB transposed-weight slots
  char* S1 = ws + 12582912;                // 16 MB : T1 -> Q -> attnT
  char* S2 = S1 + 16777216;                // 16 MB : Gsum/gated -> K -> normed
  char* S3 = S2 + 16777216;                // 16 MB : comb
  char* SC = S3 + 16777216;                // 32 MB : scores f32 (xb aliases first 16MB early)
  u16* xb = (u16*)SC;                      // bf16 x (dead before SC written)
  u8* maskb = (u8*)(SC + 33554432);        // 8 MB
  u16* SM = (u16*)(maskb + 8388608);       // small converted arrays
  char* S4 = (char*)d_out;                 // 16 MB scratch: Vt -> mem_gated (overwritten by final GEMM)

  size_t off = 0;
  auto alloc = [&](size_t n) { u16* p = SM + off; off += (n + 7) & ~(size_t)7; return p; };
  u16* c_gb1 = alloc(3072);  u16* c_gb2 = alloc(3072);
  u16* c_gwts = alloc(3);    u16* c_tsl = alloc(3);
  u16* c_ssmA = alloc(768);  u16* c_ssmBm = alloc(49152);
  u16* c_ssmC = alloc(49152); u16* c_ssmD = alloc(3072);
  u16* c_cgw1 = alloc(786432); u16* c_cgb1 = alloc(768);
  u16* c_cgw2 = alloc(768);  u16* c_cgb2 = alloc(3);
  u16* c_bq = alloc(1024);   u16* c_bk = alloc(1024);
  u16* c_bv = alloc(1024);   u16* c_bo = alloc(1024);
  u16* c_mg = alloc(1024);   u16* c_cpw1 = alloc(524288);
  u16* c_cpb1 = alloc(512);  u16* c_cpw2 = alloc(512);
  u16* c_cpb2 = alloc(1);    u16* c_lng = alloc(1024);
  u16* c_lnb = alloc(1024);  u16* c_outb = alloc(1024);
  char* tail = (char*)(SM + ((off + 7) & ~(size_t)7));
  float* Ubuf = (float*)tail;
  float* Hbuf = Ubuf + 393216;
  float* Mf = Hbuf + 393216;
  float* Mcf = Mf + 8192;
  float* cff = Mcf + 8192;
  float* cpf = cff + 32;
  u32* flags = (u32*)(cpf + 8);

  // 0. detect dtypes
  detect_k<<<1, 256, 0, stream>>>((const u32*)mgate, (const u32*)mask, flags);

  // 1. convert all small arrays + x
  {
    CvtTab tb{};
    const void* srcs[NCVT] = {gb1, gb2, gwts, tsl, ssmA, ssmBm, ssmC, ssmD, cgw1, cgb1, cgw2, cgb2,
                              bq, bk, bvp, bo, mgate, cpw1, cpb1, cpw2, cpb2, lng, lnb, outb, x};
    u16* dsts[NCVT] = {c_gb1, c_gb2, c_gwts, c_tsl, c_ssmA, c_ssmBm, c_ssmC, c_ssmD, c_cgw1, c_cgb1,
                       c_cgw2, c_cgb2, c_bq, c_bk, c_bv, c_bo, c_mg, c_cpw1, c_cpb1, c_cpw2, c_cpb2,
                       c_lng, c_lnb, c_outb, xb};
    int ns[NCVT] = {3072, 3072, 3, 3, 768, 49152, 49152, 3072, 786432, 768, 768, 3,
                    1024, 1024, 1024, 1024, 1024, 524288, 512, 512, 1, 1024, 1024, 1024, 8388608};
    for (int i = 0; i < NCVT; i++) { tb.src[i] = srcs[i]; tb.dst[i] = dsts[i]; tb.n[i] = ns[i]; }
    cvt_table<<<dim3(256, NCVT), 256, 0, stream>>>(tb, flags);
  }

  // 2. mask -> u8
  cvt_mask<<<8192, 256, 0, stream>>>(mask, (u32*)maskb, flags);

  // 3. convert+transpose gw1 x3, gw2 x3 (element offsets, dtype-independent)
  {
    TPC tp{};
    for (int i = 0; i < 3; i++) { tp.src[i] = gw1; tp.soff[i] = (long)i * MBe; tp.dst[i] = W + (size_t)i * MBe; }
    for (int i = 0; i < 3; i++) { tp.src[3 + i] = gw2; tp.soff[3 + i] = (long)i * MBe; tp.dst[3 + i] = W + (size_t)(3 + i) * MBe; }
    transpose_cvt<<<dim3(16, 16, 6), dim3(64, 4), 0, stream>>>(tp, flags);
  }

  // 4. per-gate: T1 = silu(xb@gw1t[i]+gb1[i]) ; Gsum (+)= gweights[i]*sigmoid(T1@gw2t[i]+gb2[i])
  for (int i = 0; i < 3; i++) {
    { GemmP p; p.A = xb; p.Bt = W + (size_t)i * MBe; p.C = S1; p.sAz = 0; p.sBz = 0; p.sCzB = 0;
      p.lda = 1024; p.ldb = 1024; p.ldc = 1024; p.K = 1024;
      Ep e{}; e.bias = c_gb1 + i * 1024;
      gemm_bt<0><<<dim3(8, 64, 1), 256, 0, stream>>>(p, e); }
    { GemmP p; p.A = (u16*)S1; p.Bt = W + (size_t)(3 + i) * MBe; p.C = S2; p.sAz = 0; p.sBz = 0; p.sCzB = 0;
      p.lda = 1024; p.ldb = 1024; p.ldc = 1024; p.K = 1024;
      Ep e{}; e.bias = c_gb2 + i * 1024; e.gw = c_gwts + i; e.accum = i;
      gemm_bt<1><<<dim3(8, 64, 1), 256, 0, stream>>>(p, e); }
  }

  // 5. gated = x * Gsum (in place in S2)
  gate_combine<<<8192, 256, 0, stream>>>(xb, (u16*)S2);

  // 6. context gates
  colmean<<<dim3(4, 8), 256, 0, stream>>>((u16*)S2, Mf);
  mlp_gate<<<dim3(8, 3), 256, 0, stream>>>(Mf, c_cgw1, c_cgb1, c_cgw2, c_cgb2, cff, 256);

  // 7. U then scan
  ssm_u<<<dim3(8192, 3), 64, 0, stream>>>((u16*)S2, c_ssmBm, cff, Ubuf);
  ssm_scan<<<dim3(8, 3), 64, 0, stream>>>(c_ssmA, Ubuf, Hbuf);

  // 8. comb -> S3
  comb_k<<<8192, 256, 0, stream>>>(Hbuf, c_ssmC, c_ssmD, cff, c_tsl, (u16*)S2, (u16*)S3);

  // 9. convert+transpose wq,wk,wv
  {
    TPC tp{};
    tp.src[0] = wq; tp.soff[0] = 0; tp.dst[0] = W;
    tp.src[1] = wk; tp.soff[1] = 0; tp.dst[1] = W + MBe;
    tp.src[2] = wv; tp.soff[2] = 0; tp.dst[2] = W + 2 * MBe;
    transpose_cvt<<<dim3(16, 16, 3), dim3(64, 4), 0, stream>>>(tp, flags);
  }

  // 10. Q->S1, K->S2, Vt->S4(d_out)
  { GemmP p; p.A = (u16*)S3; p.Bt = W; p.C = S1; p.sAz = 0; p.sBz = (long)MBe; p.sCzB = 0;
    p.lda = 1024; p.ldb = 1024; p.ldc = 1024; p.K = 1024;
    Ep e{}; e.bias = c_bq; e.bias1 = c_bk; e.bias2 = c_bv; e.cQ = S1; e.cK = S2; e.cV = S4;
    gemm_bt<2><<<dim3(8, 64, 3), 256, 0, stream>>>(p, e); }

  // 11. masked scores (f32) -> SC
  { GemmP p; p.A = (u16*)S1; p.Bt = (u16*)S2; p.C = SC; p.sAz = (long)MBe; p.sBz = (long)MBe;
    p.sCzB = 4194304; p.lda = 1024; p.ldb = 1024; p.ldc = 1024; p.K = 1024;
    Ep e{}; e.mask8 = maskb; e.scale = 0.03125f;
    gemm_bt<3><<<dim3(8, 8, 8), 256, 0, stream>>>(p, e); }

  // 12. softmax in place
  softmax_row<<<8192, 256, 0, stream>>>((float*)SC);

  // 13. attnT = (probs @ V)^T per batch -> S1
  { GemmP p; p.A = (u16*)SC; p.Bt = (u16*)S4; p.C = S1; p.sAz = 2097152; p.sBz = (long)MBe;
    p.sCzB = 2097152; p.lda = 2048; p.ldb = 1024; p.ldc = 1024; p.K = 1024;
    Ep e{};
    gemm_bt<4><<<dim3(8, 8, 8), 256, 0, stream>>>(p, e); }

  // 14. convert+transpose wo, out_w
  {
    TPC tp{};
    tp.src[0] = wo; tp.soff[0] = 0; tp.dst[0] = W;
    tp.src[1] = outw; tp.soff[1] = 0; tp.dst[1] = W + MBe;
    transpose_cvt<<<dim3(16, 16, 2), dim3(64, 4), 0, stream>>>(tp, flags);
  }

  // 15. mem_gated = (attnT @ wo + bo) * comb * mem_gate -> S4(d_out)
  { GemmP p; p.A = (u16*)S1; p.Bt = W; p.C = S4; p.sAz = 0; p.sBz = 0; p.sCzB = 0;
    p.lda = 1024; p.ldb = 1024; p.ldc = 1024; p.K = 1024;
    Ep e{}; e.bias = c_bo; e.comb = (u16*)S3; e.mgate = c_mg;
    gemm_bt<5><<<dim3(8, 64, 1), 256, 0, stream>>>(p, e); }

  // 16. compression gate
  colmean<<<dim3(4, 8), 256, 0, stream>>>((u16*)S4, Mcf);
  mlp_gate<<<dim3(8, 1), 256, 0, stream>>>(Mcf, c_cpw1, c_cpb1, c_cpw2, c_cpb2, cpf, 512);

  // 17. scale + layernorm -> normed -> S2
  ln_k<<<8192, 256, 0, stream>>>((u16*)S4, cpf, c_lng, c_lnb, (u16*)S2);

  // 18. out = normed @ out_w + out_b -> d_out (dtype per flags)
  { GemmP p; p.A = (u16*)S2; p.Bt = W + MBe; p.C = (char*)d_out; p.sAz = 0; p.sBz = 0; p.sCzB = 0;
    p.lda = 1024; p.ldb = 1024; p.ldc = 1024; p.K = 1024;
    Ep e{}; e.bias = c_outb; e.flags = flags;
    gemm_bt<6><<<dim3(8, 64, 1), 256, 0, stream>>>(p, e); }
}

// Round 4
// 1475.000 us; speedup vs baseline: 1.0334x; 1.0334x over previous
//
#include <hip/hip_runtime.h>

#define DEVINL __device__ __forceinline__

typedef unsigned short u16;
typedef unsigned int u32;
typedef unsigned char u8;
typedef __attribute__((ext_vector_type(8))) short short8;
typedef __attribute__((ext_vector_type(4))) float f32x4;

// ---------------- numeric helpers ----------------
DEVINL float b2f(u16 u) { union { u32 u; float f; } v; v.u = ((u32)u) << 16; return v.f; }
DEVINL u16 f2b(float f) {
  union { float f; u32 u; } v; v.f = f;
  u32 u = v.u;
  return (u16)((u + 0x7FFFu + ((u >> 16) & 1u)) >> 16);  // RNE
}
DEVINL float sigmoid_f(float x) { float c = fminf(fmaxf(x, -30.f), 30.f); return 1.f / (1.f + __expf(-c)); }
DEVINL float tanh_f(float x) { float c = fminf(fmaxf(x, -15.f), 15.f); float e = __expf(2.f * c); return (e - 1.f) / (e + 1.f); }

DEVINL void gload16(const void* g, void* l) {
  __builtin_amdgcn_global_load_lds((const __attribute__((address_space(1))) void*)g,
                                   (__attribute__((address_space(3))) void*)l, 16, 0, 0);
}

// ---------------- dtype detection ----------------
__global__ void detect_k(const u32* mg, const u32* mask, u32* flags) {
  __shared__ int any8;
  if (threadIdx.x == 0) any8 = 0;
  __syncthreads();
  for (int i = threadIdx.x; i < 4096; i += 256) { if (mask[i] > 1u) any8 = 1; }
  __syncthreads();
  if (threadIdx.x == 0) {
    flags[0] = (mg[0] == 0x3F800000u) ? 1u : 0u;
    flags[1] = any8 ? 1u : 0u;
  }
}

// ---------------- zero floats ----------------
__global__ __launch_bounds__(256) void zero_f(float* p, int n) {
  int i = blockIdx.x * 256 + threadIdx.x;
  if (i < n) p[i] = 0.f;
}

// ---------------- table-driven convert (f32->bf16 or bf16 copy) ----------------
#define NCVT 25
struct CvtTab { const void* src[NCVT]; u16* dst[NCVT]; int n[NCVT]; };

__global__ __launch_bounds__(256) void cvt_table(CvtTab tb, const u32* flags) {
  int e = blockIdx.y;
  int n = tb.n[e];
  int idx = blockIdx.x * 256 + threadIdx.x, step = gridDim.x * 256;
  if (flags[0]) {
    const float* s = (const float*)tb.src[e]; u16* d = tb.dst[e];
    for (int i = idx; i < n; i += step) d[i] = f2b(s[i]);
  } else {
    const u16* s = (const u16*)tb.src[e]; u16* d = tb.dst[e];
    for (int i = idx; i < n; i += step) d[i] = s[i];
  }
}

// ---------------- mask -> u8 (0/1) ----------------
__global__ __launch_bounds__(256) void cvt_mask(const void* src, u32* dst, const u32* flags) {
  size_t i = (size_t)blockIdx.x * 256 + threadIdx.x;
  if (flags[1]) {
    dst[i] = ((const u32*)src)[i];
  } else {
    int4 w = ((const int4*)src)[i];
    dst[i] = (w.x ? 1u : 0u) | ((w.y ? 1u : 0u) << 8) | ((w.z ? 1u : 0u) << 16) | ((w.w ? 1u : 0u) << 24);
  }
}

// ---------------- fused convert + transpose (up to 6 square 1024x1024 mats) ----------------
struct TPC { const void* src[6]; u16* dst[6]; long soff[6]; };

__global__ __launch_bounds__(256) void transpose_cvt(TPC p, const u32* flags) {
  __shared__ u16 t[64][65];
  int z = blockIdx.z, tx = threadIdx.x;
  int x0 = blockIdx.x * 64, y0 = blockIdx.y * 64;
  if (flags[0]) {
    const float* s = (const float*)p.src[z] + p.soff[z];
    for (int i = threadIdx.y; i < 64; i += 4) t[i][tx] = f2b(s[(size_t)(y0 + i) * 1024 + x0 + tx]);
  } else {
    const u16* s = (const u16*)p.src[z] + p.soff[z];
    for (int i = threadIdx.y; i < 64; i += 4) t[i][tx] = s[(size_t)(y0 + i) * 1024 + x0 + tx];
  }
  __syncthreads();
  u16* d = p.dst[z];
  for (int i = threadIdx.y; i < 64; i += 4) d[(size_t)(x0 + i) * 1024 + y0 + tx] = t[tx][i];
}

// ---------------- Bm[t][1024][16] -> BmT[48][1024] (row n = t*16+j) ----------------
__global__ __launch_bounds__(256) void bmt_k(const u16* Bm, u16* BmT) {
  int n = blockIdx.x, t = n >> 4, j = n & 15;
  for (int d = threadIdx.x; d < 1024; d += 256)
    BmT[(size_t)n * 1024 + d] = Bm[(size_t)t * 16384 + (size_t)d * 16 + j];
}

// ---------------- generic 128x128 MFMA GEMM via global_load_lds, B TRANSPOSED ([N][K]) ----------------
struct GemmP {
  const u16* A; const u16* Bt; char* C;
  long sAz, sBz;
  size_t sCzB;
  int lda, ldb, ldc, K;
};
struct Ep {
  const u16 *bias, *bias1, *bias2, *comb, *mgate, *gw;
  const u8* mask8;
  const u32* flags;
  char *cQ, *cK, *cV;
  float scale;
  int accum;
};

template <int MODE>
__global__ __launch_bounds__(256, 2) void gemm_bt(GemmP p, Ep ep) {
  __shared__ u16 As[128 * 32];
  __shared__ u16 Bs[128 * 32];
  const int tid = threadIdx.x;
  const int lane = tid & 63, wave = tid >> 6;
  const int wm = wave >> 1, wn = wave & 1;
  const int z = blockIdx.z;
  const int m0 = blockIdx.y * 128, n0 = blockIdx.x * 128;

  const char* Ab = (const char*)p.A + ((size_t)z * p.sAz + (size_t)m0 * p.lda) * 2;
  const char* Bb = (const char*)p.Bt + ((size_t)z * p.sBz + (size_t)n0 * p.ldb) * 2;

  f32x4 acc[4][4];
  const f32x4 zv = {0.f, 0.f, 0.f, 0.f};
#pragma unroll
  for (int i = 0; i < 4; i++)
#pragma unroll
    for (int j = 0; j < 4; j++) acc[i][j] = zv;

  const int lr = lane & 15;
  const int kg = (lane >> 4) * 8;
  const int ldaB = p.lda * 2, ldbB = p.ldb * 2;

  // staging geometry: byte offset o0 = wave*2048 + lane*16 (and +1024); row = o/64, kbyte = o%64
  const int o0 = wave * 2048 + lane * 16;
  const int r0 = o0 >> 6, kb0 = o0 & 63;
  const int r1 = r0 + 16, kb1 = kb0;  // o1 = o0 + 1024
  char* ldsA = (char*)As + wave * 2048;  // wave-uniform LDS base
  char* ldsB = (char*)Bs + wave * 2048;

  for (int k0 = 0; k0 < p.K; k0 += 32) {
    gload16(Ab + (size_t)r0 * ldaB + k0 * 2 + kb0, ldsA);
    gload16(Ab + (size_t)r1 * ldaB + k0 * 2 + kb1, ldsA + 1024);
    gload16(Bb + (size_t)r0 * ldbB + k0 * 2 + kb0, ldsB);
    gload16(Bb + (size_t)r1 * ldbB + k0 * 2 + kb1, ldsB + 1024);
    __syncthreads();  // drains vmcnt -> LDS tiles ready
    short8 af[4], bfr[4];
#pragma unroll
    for (int mi = 0; mi < 4; mi++) af[mi] = *(const short8*)&As[(wm * 64 + mi * 16 + lr) * 32 + kg];
#pragma unroll
    for (int ni = 0; ni < 4; ni++) bfr[ni] = *(const short8*)&Bs[(wn * 64 + ni * 16 + lr) * 32 + kg];
#pragma unroll
    for (int mi = 0; mi < 4; mi++)
#pragma unroll
      for (int ni = 0; ni < 4; ni++)
        acc[mi][ni] = __builtin_amdgcn_mfma_f32_16x16x32_bf16(af[mi], bfr[ni], acc[mi][ni], 0, 0, 0);
    __syncthreads();  // all fragment reads done before next-tile overwrite
  }

  char* Cb = p.C + (size_t)z * p.sCzB;
  const int rb = (lane >> 4) << 2;
#pragma unroll
  for (int mi = 0; mi < 4; mi++) {
#pragma unroll
    for (int ni = 0; ni < 4; ni++) {
      const int row0 = m0 + wm * 64 + mi * 16 + rb;
      const int col = n0 + wn * 64 + ni * 16 + lr;
      f32x4 v = acc[mi][ni];
      if constexpr (MODE == 0) {
        float bv = b2f(ep.bias[col]);
        u16* C = (u16*)Cb;
#pragma unroll
        for (int j = 0; j < 4; j++) { float a = v[j] + bv; C[(size_t)(row0 + j) * p.ldc + col] = f2b(a * sigmoid_f(a)); }
      } else if constexpr (MODE == 1) {
        float bv = b2f(ep.bias[col]);
        float w = b2f(ep.gw[0]);
        u16* C = (u16*)Cb;
#pragma unroll
        for (int j = 0; j < 4; j++) {
          size_t idx = (size_t)(row0 + j) * p.ldc + col;
          float t = w * sigmoid_f(v[j] + bv);
          if (ep.accum) t += b2f(C[idx]);
          C[idx] = f2b(t);
        }
      } else if constexpr (MODE == 2) {
        const u16* bp = (z == 0) ? ep.bias : ((z == 1) ? ep.bias1 : ep.bias2);
        float bv = b2f(bp[col]);
        if (z == 0) {
          u16* C = (u16*)ep.cQ;
#pragma unroll
          for (int j = 0; j < 4; j++) C[(size_t)(row0 + j) * p.ldc + col] = f2b(v[j] + bv);
        } else if (z == 1) {
          u16* C = (u16*)ep.cK;
#pragma unroll
          for (int j = 0; j < 4; j++) C[(size_t)(row0 + j) * p.ldc + col] = f2b(v[j] + bv);
        } else {
          int b = row0 >> 10, s = row0 & 1023;
          ushort4 pk;
          pk.x = f2b(v[0] + bv); pk.y = f2b(v[1] + bv); pk.z = f2b(v[2] + bv); pk.w = f2b(v[3] + bv);
          *(ushort4*)((u16*)ep.cV + (size_t)b * 1048576 + (size_t)col * 1024 + s) = pk;
        }
      } else if constexpr (MODE == 3) {
        float* C = (float*)Cb;
        const u8* mrow = ep.mask8 + (size_t)z * 1048576;
#pragma unroll
        for (int j = 0; j < 4; j++) {
          float sc = v[j] * ep.scale;
          C[(size_t)(row0 + j) * p.ldc + col] = mrow[(size_t)(row0 + j) * 1024 + col] ? sc : -1e30f;
        }
      } else if constexpr (MODE == 4) {
        ushort4 pk;
        pk.x = f2b(v[0]); pk.y = f2b(v[1]); pk.z = f2b(v[2]); pk.w = f2b(v[3]);
        *(ushort4*)((u16*)Cb + (size_t)col * 1024 + row0) = pk;
      } else if constexpr (MODE == 5) {
        float bv = b2f(ep.bias[col]);
        float mg = b2f(ep.mgate[col]);
        u16* C = (u16*)Cb;
#pragma unroll
        for (int j = 0; j < 4; j++) {
          size_t idx = (size_t)(row0 + j) * p.ldc + col;
          C[idx] = f2b((v[j] + bv) * b2f(ep.comb[idx]) * mg);
        }
      } else {  // MODE 6
        float bv = b2f(ep.bias[col]);
        if (ep.flags[0]) {
          float* C = (float*)Cb;
#pragma unroll
          for (int j = 0; j < 4; j++) C[(size_t)(row0 + j) * p.ldc + col] = v[j] + bv;
        } else {
          u16* C = (u16*)Cb;
#pragma unroll
          for (int j = 0; j < 4; j++) C[(size_t)(row0 + j) * p.ldc + col] = f2b(v[j] + bv);
        }
      }
    }
  }
}

// ---------------- ssm_u as skinny MFMA GEMM: U = tanh(cf * (gated @ Bm)) ----------------
// A = gated [8192][1024]; Bt = BmT [48][1024]; out U[t][8192][16] f32.
__global__ __launch_bounds__(256, 2) void ssm_u_mfma(const u16* A, const u16* BmT,
                                                     const float* cf, float* U) {
  __shared__ u16 As[128 * 32];   // 8 KB
  __shared__ u16 Bs[48 * 32];    // 3 KB
  const int tid = threadIdx.x;
  const int lane = tid & 63, wave = tid >> 6;
  const int m0 = blockIdx.x * 128;
  const char* Ab = (const char*)A + (size_t)m0 * 2048;
  const char* Bb = (const char*)BmT;

  f32x4 acc[2][3];
  const f32x4 zv = {0.f, 0.f, 0.f, 0.f};
#pragma unroll
  for (int i = 0; i < 2; i++)
#pragma unroll
    for (int j = 0; j < 3; j++) acc[i][j] = zv;

  const int lr = lane & 15;
  const int kg = (lane >> 4) * 8;
  const int o0 = wave * 2048 + lane * 16;
  const int r0 = o0 >> 6, kb0 = o0 & 63;
  char* ldsA = (char*)As + wave * 2048;
  const int ob = wave * 1024 + lane * 16;   // Bs offset (waves 0..2)
  const int rbn = ob >> 6, kbb = ob & 63;
  char* ldsB = (char*)Bs + wave * 1024;

  for (int k0 = 0; k0 < 1024; k0 += 32) {
    gload16(Ab + (size_t)r0 * 2048 + k0 * 2 + kb0, ldsA);
    gload16(Ab + (size_t)(r0 + 16) * 2048 + k0 * 2 + kb0, ldsA + 1024);
    if (wave < 3) gload16(Bb + (size_t)rbn * 2048 + k0 * 2 + kbb, ldsB);
    __syncthreads();
    short8 af[2], bfr[3];
#pragma unroll
    for (int mi = 0; mi < 2; mi++) af[mi] = *(const short8*)&As[(wave * 32 + mi * 16 + lr) * 32 + kg];
#pragma unroll
    for (int nf = 0; nf < 3; nf++) bfr[nf] = *(const short8*)&Bs[(nf * 16 + lr) * 32 + kg];
#pragma unroll
    for (int mi = 0; mi < 2; mi++)
#pragma unroll
      for (int nf = 0; nf < 3; nf++)
        acc[mi][nf] = __builtin_amdgcn_mfma_f32_16x16x32_bf16(af[mi], bfr[nf], acc[mi][nf], 0, 0, 0);
    __syncthreads();
  }

  const int rb = (lane >> 4) << 2;
#pragma unroll
  for (int mi = 0; mi < 2; mi++) {
#pragma unroll
    for (int nf = 0; nf < 3; nf++) {
      const int row0 = m0 + wave * 32 + mi * 16 + rb;
      f32x4 v = acc[mi][nf];
#pragma unroll
      for (int j = 0; j < 4; j++) {
        int r = row0 + j;
        float c = cf[nf * 8 + (r >> 10)];
        U[((size_t)nf * 8192 + r) * 16 + lr] = tanh_f(c * v[j]);
      }
    }
  }
}

// ---------------- gated = x * Gsum (in place over Gsum) ----------------
__global__ __launch_bounds__(256) void gate_combine(const u16* x, u16* gs) {
  size_t i = ((size_t)blockIdx.x * 256 + threadIdx.x) * 4;
  ushort4 xv = *(const ushort4*)(x + i);
  ushort4 a = *(const ushort4*)(gs + i);
  ushort4 o;
  o.x = f2b(b2f(xv.x) * b2f(a.x));
  o.y = f2b(b2f(xv.y) * b2f(a.y));
  o.z = f2b(b2f(xv.z) * b2f(a.z));
  o.w = f2b(b2f(xv.w) * b2f(a.w));
  *(ushort4*)(gs + i) = o;
}

// ---------------- column sum (atomic partials): Mo[b][d] += sum over 128 rows ----------------
__global__ __launch_bounds__(256) void colmean_at(const u16* X, float* Mo) {
  int b = blockIdx.y, g = blockIdx.x;
  int c = threadIdx.x * 4;
  const u16* p = X + (size_t)b * 1048576 + (size_t)g * 131072 + c;
  float s0 = 0, s1 = 0, s2 = 0, s3 = 0;
  for (int i = 0; i < 128; i++) {
    ushort4 v = *(const ushort4*)(p + (size_t)i * 1024);
    s0 += b2f(v.x); s1 += b2f(v.y); s2 += b2f(v.z); s3 += b2f(v.w);
  }
  float* o = Mo + b * 1024 + c;
  atomicAdd(o + 0, s0); atomicAdd(o + 1, s1); atomicAdd(o + 2, s2); atomicAdd(o + 3, s3);
}

// ---------------- tiny gate MLP, coalesced (Mv holds column SUMS) ----------------
__global__ __launch_bounds__(256) void mlp2(const float* Mv, const u16* W1, const u16* b1,
                                            const u16* W2, const u16* b2, float* outv, int H) {
  int b = blockIdx.x, t = blockIdx.y, tid = threadIdx.x;
  __shared__ float mv[1024];
  __shared__ float red[256];
  for (int i = tid; i < 1024; i += 256) mv[i] = Mv[b * 1024 + i] * (1.f / 1024.f);
  __syncthreads();
  const u16* W1t = W1 + (size_t)t * 1024 * H;
  float a0 = 0.f, a1 = 0.f;
#pragma unroll 4
  for (int d = 0; d < 1024; d++) {
    float m = mv[d];
    a0 += m * b2f(W1t[(size_t)d * H + tid]);
    if (H > 256) a1 += m * b2f(W1t[(size_t)d * H + tid + 256]);
  }
  float acc;
  { float a = a0 + b2f(b1[t * H + tid]); acc = (a * sigmoid_f(a)) * b2f(W2[t * H + tid]); }
  if (H > 256) { float a = a1 + b2f(b1[t * H + tid + 256]); acc += (a * sigmoid_f(a)) * b2f(W2[t * H + tid + 256]); }
  red[tid] = acc;
  __syncthreads();
  for (int s = 128; s > 0; s >>= 1) { if (tid < s) red[tid] += red[tid + s]; __syncthreads(); }
  if (tid == 0) outv[t * 8 + b] = sigmoid_f(red[0] + b2f(b2[t]));
}

// ---------------- sequential scan: h = tanh(h@A) + U[s]; 4-lane-split matvec ----------------
__global__ __launch_bounds__(64) void ssm_scan(const u16* Aw, const float* U, float* Ho) {
  int b = blockIdx.x, t = blockIdx.y, lane = threadIdx.x;
  int j = lane & 15, seg = lane >> 4;
  float a[4];
#pragma unroll
  for (int kk = 0; kk < 4; kk++) a[kk] = b2f(Aw[t * 256 + (seg * 4 + kk) * 16 + j]);
  const float* Ur = U + ((size_t)t * 8192 + (size_t)b * 1024) * 16;
  float* Hr = Ho + ((size_t)t * 8192 + (size_t)b * 1024) * 16;
  float h = 0.f;
  float ucur = Ur[j];
  for (int s = 0; s < 1024; s++) {
    float unxt = (s < 1023) ? Ur[(size_t)(s + 1) * 16 + j] : 0.f;
    float part = 0.f;
#pragma unroll
    for (int kk = 0; kk < 4; kk++) part += __shfl(h, seg * 4 + kk) * a[kk];
    float xv = part + __shfl_xor(part, 16);
    xv += __shfl_xor(xv, 32);
    h = tanh_f(xv) + ucur;
    if (lane < 16) Hr[(size_t)s * 16 + j] = h;
    ucur = unxt;
  }
}

// ---------------- comb = sum_t tw[t]*(tanh(H@C[t]) + Dv[t]*cf*gated) ----------------
__global__ __launch_bounds__(256) void comb_k(const float* Hbuf, const u16* C, const u16* Dv,
                                              const float* cf, const u16* tsl, const u16* gated,
                                              u16* comb) {
  int r = blockIdx.x, tid = threadIdx.x;
  int b = r >> 10;
  __shared__ float Hs[3][16];
  __shared__ float tw[3];
  if (tid < 48) Hs[tid >> 4][tid & 15] = Hbuf[((size_t)(tid >> 4) * 8192 + r) * 16 + (tid & 15)];
  if (tid == 0) {
    float l0 = b2f(tsl[0]), l1 = b2f(tsl[1]), l2 = b2f(tsl[2]);
    float m = fmaxf(l0, fmaxf(l1, l2));
    float e0 = __expf(l0 - m), e1 = __expf(l1 - m), e2 = __expf(l2 - m);
    float s = e0 + e1 + e2;
    tw[0] = e0 / s; tw[1] = e1 / s; tw[2] = e2 / s;
  }
  __syncthreads();
  int d0 = tid * 4;
  ushort4 gv = *(const ushort4*)(gated + (size_t)r * 1024 + d0);
  float g0 = b2f(gv.x), g1 = b2f(gv.y), g2 = b2f(gv.z), g3v = b2f(gv.w);
  float o0 = 0, o1 = 0, o2 = 0, o3 = 0;
#pragma unroll
  for (int t = 0; t < 3; t++) {
    float w = tw[t], cfv = cf[t * 8 + b];
    float dA = 0, dB = 0, dC = 0, dD = 0;
#pragma unroll
    for (int k = 0; k < 16; k++) {
      float h = Hs[t][k];
      ushort4 cv = *(const ushort4*)(C + ((size_t)t * 16 + k) * 1024 + d0);
      dA += h * b2f(cv.x); dB += h * b2f(cv.y); dC += h * b2f(cv.z); dD += h * b2f(cv.w);
    }
    float dvw = w * cfv;
    o0 += w * tanh_f(dA) + dvw * b2f(Dv[t * 1024 + d0 + 0]) * g0;
    o1 += w * tanh_f(dB) + dvw * b2f(Dv[t * 1024 + d0 + 1]) * g1;
    o2 += w * tanh_f(dC) + dvw * b2f(Dv[t * 1024 + d0 + 2]) * g2;
    o3 += w * tanh_f(dD) + dvw * b2f(Dv[t * 1024 + d0 + 3]) * g3v;
  }
  ushort4 ov;
  ov.x = f2b(o0); ov.y = f2b(o1); ov.z = f2b(o2); ov.w = f2b(o3);
  *(ushort4*)(comb + (size_t)r * 1024 + d0) = ov;
}

// ---------------- row softmax, IN PLACE: f32 row -> bf16 in low half ----------------
__global__ __launch_bounds__(256) void softmax_row(float* S) {
  int r = blockIdx.x, tid = threadIdx.x;
  float* row = S + (size_t)r * 1024;
  float4 v = ((const float4*)row)[tid];
  float mx = fmaxf(fmaxf(v.x, v.y), fmaxf(v.z, v.w));
  for (int o = 32; o; o >>= 1) mx = fmaxf(mx, __shfl_xor(mx, o));
  __shared__ float sm[4], ssum[4];
  int ln = tid & 63, wv = tid >> 6;
  if (!ln) sm[wv] = mx;
  __syncthreads();
  mx = fmaxf(fmaxf(sm[0], sm[1]), fmaxf(sm[2], sm[3]));
  float e0 = __expf(v.x - mx), e1 = __expf(v.y - mx), e2 = __expf(v.z - mx), e3 = __expf(v.w - mx);
  float s = e0 + e1 + e2 + e3;
  for (int o = 32; o; o >>= 1) s += __shfl_xor(s, o);
  if (!ln) ssum[wv] = s;
  __syncthreads();
  s = ssum[0] + ssum[1] + ssum[2] + ssum[3];
  float inv = 1.f / s;
  ushort4 pk;
  pk.x = f2b(e0 * inv); pk.y = f2b(e1 * inv); pk.z = f2b(e2 * inv); pk.w = f2b(e3 * inv);
  __syncthreads();
  ((ushort4*)row)[tid] = pk;
}

// ---------------- comp = mem_gated*cpf ; layernorm ----------------
__global__ __launch_bounds__(256) void ln_k(const u16* MG, const float* cpf, const u16* lng,
                                            const u16* lnb, u16* outp) {
  int r = blockIdx.x, tid = threadIdx.x;
  float cfv = cpf[r >> 10];
  ushort4 m4 = *(const ushort4*)(MG + (size_t)r * 1024 + tid * 4);
  float c0 = b2f(m4.x) * cfv, c1 = b2f(m4.y) * cfv, c2 = b2f(m4.z) * cfv, c3 = b2f(m4.w) * cfv;
  float s = c0 + c1 + c2 + c3;
  float q = c0 * c0 + c1 * c1 + c2 * c2 + c3 * c3;
  int ln = tid & 63, wv = tid >> 6;
  for (int o = 32; o; o >>= 1) { s += __shfl_xor(s, o); q += __shfl_xor(q, o); }
  __shared__ float ss[4], qq[4];
  if (!ln) { ss[wv] = s; qq[wv] = q; }
  __syncthreads();
  s = ss[0] + ss[1] + ss[2] + ss[3];
  q = qq[0] + qq[1] + qq[2] + qq[3];
  float mu = s * (1.f / 1024.f);
  float var = q * (1.f / 1024.f) - mu * mu;
  float inv = rsqrtf(fmaxf(var, 0.f) + 1e-5f);
  int d = tid * 4;
  ushort4 ov;
  ov.x = f2b((c0 - mu) * inv * b2f(lng[d + 0]) + b2f(lnb[d + 0]));
  ov.y = f2b((c1 - mu) * inv * b2f(lng[d + 1]) + b2f(lnb[d + 1]));
  ov.z = f2b((c2 - mu) * inv * b2f(lng[d + 2]) + b2f(lnb[d + 2]));
  ov.w = f2b((c3 - mu) * inv * b2f(lng[d + 3]) + b2f(lnb[d + 3]));
  *(ushort4*)(outp + (size_t)r * 1024 + d) = ov;
}

// =================================================================================
extern "C" void kernel_launch(void* const* d_in, const int* in_sizes, int n_in,
                              void* d_out, int out_size, void* d_ws, size_t ws_size,
                              hipStream_t stream) {
  (void)in_sizes; (void)n_in; (void)out_size; (void)ws_size;
  const void* x = d_in[0];
  const void* mask = d_in[1];
  const void* tsl = d_in[2];
  const void* gw1 = d_in[3];
  const void* gb1 = d_in[4];
  const void* gw2 = d_in[5];
  const void* gb2 = d_in[6];
  const void* gwts = d_in[7];
  const void* ssmA = d_in[8];
  const void* ssmBm = d_in[9];
  const void* ssmC = d_in[10];
  const void* ssmD = d_in[11];
  const void* cgw1 = d_in[12];
  const void* cgb1 = d_in[13];
  const void* cgw2 = d_in[14];
  const void* cgb2 = d_in[15];
  const void* wq = d_in[16]; const void* bq = d_in[17];
  const void* wk = d_in[18]; const void* bk = d_in[19];
  const void* wv = d_in[20]; const void* bvp = d_in[21];
  const void* wo = d_in[22]; const void* bo = d_in[23];
  const void* mgate = d_in[24];
  const void* cpw1 = d_in[25];
  const void* cpb1 = d_in[26];
  const void* cpw2 = d_in[27];
  const void* cpb2 = d_in[28];
  const void* lng = d_in[29];
  const void* lnb = d_in[30];
  const void* outw = d_in[31];
  const void* outb = d_in[32];

  // ---- workspace layout ----
  char* ws = (char*)d_ws;
  const size_t MBe = 1048576;
  u16* W = (u16*)ws;                       // 6 x 2MB transposed-weight slots
  char* S1 = ws + 12582912;                // 16 MB : T1 -> Q -> attnT
  char* S2 = S1 + 16777216;                // 16 MB : Gsum/gated -> K -> normed
  char* S3 = S2 + 16777216;                // 16 MB : comb
  char* SC = S3 + 16777216;                // 32 MB : scores f32 (xb aliases first 16MB early)
  u16* xb = (u16*)SC;                      // bf16 x (dead before SC written)
  u8* maskb = (u8*)(SC + 33554432);        // 8 MB
  u16* SM = (u16*)(maskb + 8388608);       // small converted arrays
  char* S4 = (char*)d_out;                 // 16 MB scratch: Vt -> mem_gated (overwritten by final GEMM)

  size_t off = 0;
  auto alloc = [&](size_t n) { u16* p = SM + off; off += (n + 7) & ~(size_t)7; return p; };
  u16* c_gb1 = alloc(3072);  u16* c_gb2 = alloc(3072);
  u16* c_gwts = alloc(3);    u16* c_tsl = alloc(3);
  u16* c_ssmA = alloc(768);  u16* c_ssmBm = alloc(49152);
  u16* c_ssmC = alloc(49152); u16* c_ssmD = alloc(3072);
  u16* c_cgw1 = alloc(786432); u16* c_cgb1 = alloc(768);
  u16* c_cgw2 = alloc(768);  u16* c_cgb2 = alloc(3);
  u16* c_bq = alloc(1024);   u16* c_bk = alloc(1024);
  u16* c_bv = alloc(1024);   u16* c_bo = alloc(1024);
  u16* c_mg = alloc(1024);   u16* c_cpw1 = alloc(524288);
  u16* c_cpb1 = alloc(512);  u16* c_cpw2 = alloc(512);
  u16* c_cpb2 = alloc(1);    u16* c_lng = alloc(1024);
  u16* c_lnb = alloc(1024);  u16* c_outb = alloc(1024);
  u16* BmT = alloc(49152);   // [48][1024]
  char* tail = (char*)(SM + ((off + 7) & ~(size_t)7));
  float* Ubuf = (float*)tail;
  float* Hbuf = Ubuf + 393216;
  float* Mf = Hbuf + 393216;       // column sums (gated)
  float* Mcf = Mf + 8192;          // column sums (mem_gated)
  float* cff = Mcf + 8192;
  float* cpf = cff + 32;
  u32* flags = (u32*)(cpf + 8);

  // 0. detect dtypes; zero the atomic accumulators (Mf,Mcf contiguous: 16384 floats)
  detect_k<<<1, 256, 0, stream>>>((const u32*)mgate, (const u32*)mask, flags);
  zero_f<<<64, 256, 0, stream>>>(Mf, 16384);

  // 1. convert all small arrays + x
  {
    CvtTab tb{};
    const void* srcs[NCVT] = {gb1, gb2, gwts, tsl, ssmA, ssmBm, ssmC, ssmD, cgw1, cgb1, cgw2, cgb2,
                              bq, bk, bvp, bo, mgate, cpw1, cpb1, cpw2, cpb2, lng, lnb, outb, x};
    u16* dsts[NCVT] = {c_gb1, c_gb2, c_gwts, c_tsl, c_ssmA, c_ssmBm, c_ssmC, c_ssmD, c_cgw1, c_cgb1,
                       c_cgw2, c_cgb2, c_bq, c_bk, c_bv, c_bo, c_mg, c_cpw1, c_cpb1, c_cpw2, c_cpb2,
                       c_lng, c_lnb, c_outb, xb};
    int ns[NCVT] = {3072, 3072, 3, 3, 768, 49152, 49152, 3072, 786432, 768, 768, 3,
                    1024, 1024, 1024, 1024, 1024, 524288, 512, 512, 1, 1024, 1024, 1024, 8388608};
    for (int i = 0; i < NCVT; i++) { tb.src[i] = srcs[i]; tb.dst[i] = dsts[i]; tb.n[i] = ns[i]; }
    cvt_table<<<dim3(256, NCVT), 256, 0, stream>>>(tb, flags);
  }

  // 2. mask -> u8 ; BmT
  cvt_mask<<<8192, 256, 0, stream>>>(mask, (u32*)maskb, flags);
  bmt_k<<<48, 256, 0, stream>>>(c_ssmBm, BmT);

  // 3. convert+transpose gw1 x3, gw2 x3
  {
    TPC tp{};
    for (int i = 0; i < 3; i++) { tp.src[i] = gw1; tp.soff[i] = (long)i * MBe; tp.dst[i] = W + (size_t)i * MBe; }
    for (int i = 0; i < 3; i++) { tp.src[3 + i] = gw2; tp.soff[3 + i] = (long)i * MBe; tp.dst[3 + i] = W + (size_t)(3 + i) * MBe; }
    transpose_cvt<<<dim3(16, 16, 6), dim3(64, 4), 0, stream>>>(tp, flags);
  }

  // 4. per-gate: T1 = silu(xb@gw1t[i]+gb1[i]) ; Gsum (+)= gweights[i]*sigmoid(T1@gw2t[i]+gb2[i])
  for (int i = 0; i < 3; i++) {
    { GemmP p; p.A = xb; p.Bt = W + (size_t)i * MBe; p.C = S1; p.sAz = 0; p.sBz = 0; p.sCzB = 0;
      p.lda = 1024; p.ldb = 1024; p.ldc = 1024; p.K = 1024;
      Ep e{}; e.bias = c_gb1 + i * 1024;
      gemm_bt<0><<<dim3(8, 64, 1), 256, 0, stream>>>(p, e); }
    { GemmP p; p.A = (u16*)S1; p.Bt = W + (size_t)(3 + i) * MBe; p.C = S2; p.sAz = 0; p.sBz = 0; p.sCzB = 0;
      p.lda = 1024; p.ldb = 1024; p.ldc = 1024; p.K = 1024;
      Ep e{}; e.bias = c_gb2 + i * 1024; e.gw = c_gwts + i; e.accum = i;
      gemm_bt<1><<<dim3(8, 64, 1), 256, 0, stream>>>(p, e); }
  }

  // 5. gated = x * Gsum (in place in S2)
  gate_combine<<<8192, 256, 0, stream>>>(xb, (u16*)S2);

  // 6. context gates
  colmean_at<<<dim3(8, 8), 256, 0, stream>>>((u16*)S2, Mf);
  mlp2<<<dim3(8, 3), 256, 0, stream>>>(Mf, c_cgw1, c_cgb1, c_cgw2, c_cgb2, cff, 256);

  // 7. U (skinny MFMA) then scan
  ssm_u_mfma<<<64, 256, 0, stream>>>((u16*)S2, BmT, cff, Ubuf);
  ssm_scan<<<dim3(8, 3), 64, 0, stream>>>(c_ssmA, Ubuf, Hbuf);

  // 8. comb -> S3
  comb_k<<<8192, 256, 0, stream>>>(Hbuf, c_ssmC, c_ssmD, cff, c_tsl, (u16*)S2, (u16*)S3);

  // 9. convert+transpose wq,wk,wv
  {
    TPC tp{};
    tp.src[0] = wq; tp.soff[0] = 0; tp.dst[0] = W;
    tp.src[1] = wk; tp.soff[1] = 0; tp.dst[1] = W + MBe;
    tp.src[2] = wv; tp.soff[2] = 0; tp.dst[2] = W + 2 * MBe;
    transpose_cvt<<<dim3(16, 16, 3), dim3(64, 4), 0, stream>>>(tp, flags);
  }

  // 10. Q->S1, K->S2, Vt->S4(d_out)
  { GemmP p; p.A = (u16*)S3; p.Bt = W; p.C = S1; p.sAz = 0; p.sBz = (long)MBe; p.sCzB = 0;
    p.lda = 1024; p.ldb = 1024; p.ldc = 1024; p.K = 1024;
    Ep e{}; e.bias = c_bq; e.bias1 = c_bk; e.bias2 = c_bv; e.cQ = S1; e.cK = S2; e.cV = S4;
    gemm_bt<2><<<dim3(8, 64, 3), 256, 0, stream>>>(p, e); }

  // 11. masked scores (f32) -> SC
  { GemmP p; p.A = (u16*)S1; p.Bt = (u16*)S2; p.C = SC; p.sAz = (long)MBe; p.sBz = (long)MBe;
    p.sCzB = 4194304; p.lda = 1024; p.ldb = 1024; p.ldc = 1024; p.K = 1024;
    Ep e{}; e.mask8 = maskb; e.scale = 0.03125f;
    gemm_bt<3><<<dim3(8, 8, 8), 256, 0, stream>>>(p, e); }

  // 12. softmax in place
  softmax_row<<<8192, 256, 0, stream>>>((float*)SC);

  // 13. attnT = (probs @ V)^T per batch -> S1
  { GemmP p; p.A = (u16*)SC; p.Bt = (u16*)S4; p.C = S1; p.sAz = 2097152; p.sBz = (long)MBe;
    p.sCzB = 2097152; p.lda = 2048; p.ldb = 1024; p.ldc = 1024; p.K = 1024;
    Ep e{};
    gemm_bt<4><<<dim3(8, 8, 8), 256, 0, stream>>>(p, e); }

  // 14. convert+transpose wo, out_w
  {
    TPC tp{};
    tp.src[0] = wo; tp.soff[0] = 0; tp.dst[0] = W;
    tp.src[1] = outw; tp.soff[1] = 0; tp.dst[1] = W + MBe;
    transpose_cvt<<<dim3(16, 16, 2), dim3(64, 4), 0, stream>>>(tp, flags);
  }

  // 15. mem_gated = (attnT @ wo + bo) * comb * mem_gate -> S4(d_out)
  { GemmP p; p.A = (u16*)S1; p.Bt = W; p.C = S4; p.sAz = 0; p.sBz = 0; p.sCzB = 0;
    p.lda = 1024; p.ldb = 1024; p.ldc = 1024; p.K = 1024;
    Ep e{}; e.bias = c_bo; e.comb = (u16*)S3; e.mgate = c_mg;
    gemm_bt<5><<<dim3(8, 64, 1), 256, 0, stream>>>(p, e); }

  // 16. compression gate
  colmean_at<<<dim3(8, 8), 256, 0, stream>>>((u16*)S4, Mcf);
  mlp2<<<dim3(8, 1), 256, 0, stream>>>(Mcf, c_cpw1, c_cpb1, c_cpw2, c_cpb2, cpf, 512);

  // 17. scale + layernorm -> normed -> S2
  ln_k<<<8192, 256, 0, stream>>>((u16*)S4, cpf, c_lng, c_lnb, (u16*)S2);

  // 18. out = normed @ out_w + out_b -> d_out (dtype per flags)
  { GemmP p; p.A = (u16*)S2; p.Bt = W + MBe; p.C = (char*)d_out; p.sAz = 0; p.sBz = 0; p.sCzB = 0;
    p.lda = 1024; p.ldb = 1024; p.ldc = 1024; p.K = 1024;
    Ep e{}; e.bias = c_outb; e.flags = flags;
    gemm_bt<6><<<dim3(8, 64, 1), 256, 0, stream>>>(p, e); }
}

// Round 5
// 1267.610 us; speedup vs baseline: 1.2024x; 1.1636x over previous
//
#include <hip/hip_runtime.h>

#define DEVINL __device__ __forceinline__

typedef unsigned short u16;
typedef unsigned int u32;
typedef unsigned char u8;
typedef __attribute__((ext_vector_type(8))) short short8;
typedef __attribute__((ext_vector_type(4))) float f32x4;

// ---------------- numeric helpers ----------------
DEVINL float b2f(u16 u) { union { u32 u; float f; } v; v.u = ((u32)u) << 16; return v.f; }
DEVINL u16 f2b(float f) {
  union { float f; u32 u; } v; v.f = f;
  u32 u = v.u;
  return (u16)((u + 0x7FFFu + ((u >> 16) & 1u)) >> 16);  // RNE
}
DEVINL float sigmoid_f(float x) { float c = fminf(fmaxf(x, -30.f), 30.f); return 1.f / (1.f + __expf(-c)); }
DEVINL float tanh_f(float x) { float c = fminf(fmaxf(x, -15.f), 15.f); float e = __expf(2.f * c); return (e - 1.f) / (e + 1.f); }
DEVINL float tanh_fast(float x) {
  float c = fminf(fmaxf(x, -15.f), 15.f);
  float e = __expf(2.f * c);
  return 1.f - 2.f * __builtin_amdgcn_rcpf(e + 1.f);
}

DEVINL void gload16(const void* g, void* l) {
  __builtin_amdgcn_global_load_lds((const __attribute__((address_space(1))) void*)g,
                                   (__attribute__((address_space(3))) void*)l, 16, 0, 0);
}

// ---------------- dtype detection ----------------
__global__ void detect_k(const u32* mg, const u32* mask, u32* flags) {
  __shared__ int any8;
  if (threadIdx.x == 0) any8 = 0;
  __syncthreads();
  for (int i = threadIdx.x; i < 4096; i += 256) { if (mask[i] > 1u) any8 = 1; }
  __syncthreads();
  if (threadIdx.x == 0) {
    flags[0] = (mg[0] == 0x3F800000u) ? 1u : 0u;
    flags[1] = any8 ? 1u : 0u;
  }
}

// ---------------- zero floats ----------------
__global__ __launch_bounds__(256) void zero_f(float* p, int n) {
  int i = blockIdx.x * 256 + threadIdx.x;
  if (i < n) p[i] = 0.f;
}

// ---------------- table-driven convert (f32->bf16 or bf16 copy) ----------------
#define NCVT 25
struct CvtTab { const void* src[NCVT]; u16* dst[NCVT]; int n[NCVT]; };

__global__ __launch_bounds__(256) void cvt_table(CvtTab tb, const u32* flags) {
  int e = blockIdx.y;
  int n = tb.n[e];
  int idx = blockIdx.x * 256 + threadIdx.x, step = gridDim.x * 256;
  if (flags[0]) {
    const float* s = (const float*)tb.src[e]; u16* d = tb.dst[e];
    for (int i = idx; i < n; i += step) d[i] = f2b(s[i]);
  } else {
    const u16* s = (const u16*)tb.src[e]; u16* d = tb.dst[e];
    for (int i = idx; i < n; i += step) d[i] = s[i];
  }
}

// ---------------- mask -> u8 (0/1) ----------------
__global__ __launch_bounds__(256) void cvt_mask(const void* src, u32* dst, const u32* flags) {
  size_t i = (size_t)blockIdx.x * 256 + threadIdx.x;
  if (flags[1]) {
    dst[i] = ((const u32*)src)[i];
  } else {
    int4 w = ((const int4*)src)[i];
    dst[i] = (w.x ? 1u : 0u) | ((w.y ? 1u : 0u) << 8) | ((w.z ? 1u : 0u) << 16) | ((w.w ? 1u : 0u) << 24);
  }
}

// ---------------- fused convert + transpose (up to 6 square 1024x1024 mats) ----------------
struct TPC { const void* src[6]; u16* dst[6]; long soff[6]; };

__global__ __launch_bounds__(256) void transpose_cvt(TPC p, const u32* flags) {
  __shared__ u16 t[64][65];
  int z = blockIdx.z, tx = threadIdx.x;
  int x0 = blockIdx.x * 64, y0 = blockIdx.y * 64;
  if (flags[0]) {
    const float* s = (const float*)p.src[z] + p.soff[z];
    for (int i = threadIdx.y; i < 64; i += 4) t[i][tx] = f2b(s[(size_t)(y0 + i) * 1024 + x0 + tx]);
  } else {
    const u16* s = (const u16*)p.src[z] + p.soff[z];
    for (int i = threadIdx.y; i < 64; i += 4) t[i][tx] = s[(size_t)(y0 + i) * 1024 + x0 + tx];
  }
  __syncthreads();
  u16* d = p.dst[z];
  for (int i = threadIdx.y; i < 64; i += 4) d[(size_t)(x0 + i) * 1024 + y0 + tx] = t[tx][i];
}

// ---------------- Bm[t][1024][16] -> BmT[48][1024] ----------------
__global__ __launch_bounds__(256) void bmt_k(const u16* Bm, u16* BmT) {
  int n = blockIdx.x, t = n >> 4, j = n & 15;
  for (int d = threadIdx.x; d < 1024; d += 256)
    BmT[(size_t)n * 1024 + d] = Bm[(size_t)t * 16384 + (size_t)d * 16 + j];
}

// ---------------- 128x128 MFMA GEMM, 512 threads (8 waves: 4m x 2n), B TRANSPOSED ----------------
struct GemmP {
  const u16* A; const u16* Bt; char* C;
  long sAz, sBz;
  size_t sCzB;
  int lda, ldb, ldc, K;
};
struct Ep {
  const u16 *bias, *bias1, *bias2, *comb, *mgate, *gw;
  const u8* mask8;
  const u32* flags;
  char *cQ, *cK, *cV;
  float scale;
  int accum;
};

template <int MODE>
__global__ __launch_bounds__(512, 4) void gemm_bt(GemmP p, Ep ep) {
  __shared__ u16 As[128 * 32];
  __shared__ u16 Bs[128 * 32];
  const int tid = threadIdx.x;
  const int lane = tid & 63, wave = tid >> 6;   // 0..7
  const int wm = wave & 3, wn = wave >> 2;      // 4 m-groups x 2 n-groups
  const int z = blockIdx.z;
  const int m0 = blockIdx.y * 128, n0 = blockIdx.x * 128;

  const char* Ab = (const char*)p.A + ((size_t)z * p.sAz + (size_t)m0 * p.lda) * 2;
  const char* Bb = (const char*)p.Bt + ((size_t)z * p.sBz + (size_t)n0 * p.ldb) * 2;

  f32x4 acc[2][4];
  const f32x4 zv = {0.f, 0.f, 0.f, 0.f};
#pragma unroll
  for (int i = 0; i < 2; i++)
#pragma unroll
    for (int j = 0; j < 4; j++) acc[i][j] = zv;

  const int lr = lane & 15;
  const int kg = (lane >> 4) * 8;
  const int ldaB = p.lda * 2, ldbB = p.ldb * 2;

  // 512 threads x 16B = 8KB = one full 128x32 bf16 tile per matrix per K-step
  const int o0 = tid * 16;
  const int r0 = o0 >> 6, kb0 = o0 & 63;
  char* ldsA = (char*)As + wave * 1024;  // wave-uniform base; lane*16 implicit
  char* ldsB = (char*)Bs + wave * 1024;

  for (int k0 = 0; k0 < p.K; k0 += 32) {
    gload16(Ab + (size_t)r0 * ldaB + k0 * 2 + kb0, ldsA);
    gload16(Bb + (size_t)r0 * ldbB + k0 * 2 + kb0, ldsB);
    __syncthreads();
    short8 af[2], bfr[4];
#pragma unroll
    for (int mi = 0; mi < 2; mi++) af[mi] = *(const short8*)&As[(wm * 32 + mi * 16 + lr) * 32 + kg];
#pragma unroll
    for (int ni = 0; ni < 4; ni++) bfr[ni] = *(const short8*)&Bs[(wn * 64 + ni * 16 + lr) * 32 + kg];
#pragma unroll
    for (int mi = 0; mi < 2; mi++)
#pragma unroll
      for (int ni = 0; ni < 4; ni++)
        acc[mi][ni] = __builtin_amdgcn_mfma_f32_16x16x32_bf16(af[mi], bfr[ni], acc[mi][ni], 0, 0, 0);
    __syncthreads();
  }

  char* Cb = p.C + (size_t)z * p.sCzB;
  const int rb = (lane >> 4) << 2;
#pragma unroll
  for (int mi = 0; mi < 2; mi++) {
#pragma unroll
    for (int ni = 0; ni < 4; ni++) {
      const int row0 = m0 + wm * 32 + mi * 16 + rb;
      const int col = n0 + wn * 64 + ni * 16 + lr;
      f32x4 v = acc[mi][ni];
      if constexpr (MODE == 0) {           // T1 = silu(acc + gb1[z]), z-batched
        float bv = b2f(ep.bias[z * 1024 + col]);
        u16* C = (u16*)Cb;
#pragma unroll
        for (int j = 0; j < 4; j++) { float a = v[j] + bv; C[(size_t)(row0 + j) * p.ldc + col] = f2b(a * sigmoid_f(a)); }
      } else if constexpr (MODE == 1) {    // Gsum (+)= gw*sigmoid(acc+bias)
        float bv = b2f(ep.bias[col]);
        float w = b2f(ep.gw[0]);
        u16* C = (u16*)Cb;
#pragma unroll
        for (int j = 0; j < 4; j++) {
          size_t idx = (size_t)(row0 + j) * p.ldc + col;
          float t = w * sigmoid_f(v[j] + bv);
          if (ep.accum) t += b2f(C[idx]);
          C[idx] = f2b(t);
        }
      } else if constexpr (MODE == 2) {    // QKV; z==2 -> transposed V store
        const u16* bp = (z == 0) ? ep.bias : ((z == 1) ? ep.bias1 : ep.bias2);
        float bv = b2f(bp[col]);
        if (z == 0) {
          u16* C = (u16*)ep.cQ;
#pragma unroll
          for (int j = 0; j < 4; j++) C[(size_t)(row0 + j) * p.ldc + col] = f2b(v[j] + bv);
        } else if (z == 1) {
          u16* C = (u16*)ep.cK;
#pragma unroll
          for (int j = 0; j < 4; j++) C[(size_t)(row0 + j) * p.ldc + col] = f2b(v[j] + bv);
        } else {
          int b = row0 >> 10, s = row0 & 1023;
          ushort4 pk;
          pk.x = f2b(v[0] + bv); pk.y = f2b(v[1] + bv); pk.z = f2b(v[2] + bv); pk.w = f2b(v[3] + bv);
          *(ushort4*)((u16*)ep.cV + (size_t)b * 1048576 + (size_t)col * 1024 + s) = pk;
        }
      } else if constexpr (MODE == 3) {    // masked scores f32
        float* C = (float*)Cb;
        const u8* mrow = ep.mask8 + (size_t)z * 1048576;
#pragma unroll
        for (int j = 0; j < 4; j++) {
          float sc = v[j] * ep.scale;
          C[(size_t)(row0 + j) * p.ldc + col] = mrow[(size_t)(row0 + j) * 1024 + col] ? sc : -1e30f;
        }
      } else if constexpr (MODE == 4) {    // PV transposed store
        ushort4 pk;
        pk.x = f2b(v[0]); pk.y = f2b(v[1]); pk.z = f2b(v[2]); pk.w = f2b(v[3]);
        *(ushort4*)((u16*)Cb + (size_t)col * 1024 + row0) = pk;
      } else if constexpr (MODE == 5) {    // mem_gated
        float bv = b2f(ep.bias[col]);
        float mg = b2f(ep.mgate[col]);
        u16* C = (u16*)Cb;
#pragma unroll
        for (int j = 0; j < 4; j++) {
          size_t idx = (size_t)(row0 + j) * p.ldc + col;
          C[idx] = f2b((v[j] + bv) * b2f(ep.comb[idx]) * mg);
        }
      } else {  // MODE 6: final out, dtype per flags
        float bv = b2f(ep.bias[col]);
        if (ep.flags[0]) {
          float* C = (float*)Cb;
#pragma unroll
          for (int j = 0; j < 4; j++) C[(size_t)(row0 + j) * p.ldc + col] = v[j] + bv;
        } else {
          u16* C = (u16*)Cb;
#pragma unroll
          for (int j = 0; j < 4; j++) C[(size_t)(row0 + j) * p.ldc + col] = f2b(v[j] + bv);
        }
      }
    }
  }
}

// ---------------- ssm_u: skinny MFMA, writes U TRANSPOSED [t][b][j][s] f32 ----------------
__global__ __launch_bounds__(256, 2) void ssm_u_mfma(const u16* A, const u16* BmT,
                                                     const float* cf, float* U) {
  __shared__ u16 As[128 * 32];
  __shared__ u16 Bs[48 * 32];
  const int tid = threadIdx.x;
  const int lane = tid & 63, wave = tid >> 6;
  const int m0 = blockIdx.x * 128;
  const char* Ab = (const char*)A + (size_t)m0 * 2048;
  const char* Bb = (const char*)BmT;

  f32x4 acc[2][3];
  const f32x4 zv = {0.f, 0.f, 0.f, 0.f};
#pragma unroll
  for (int i = 0; i < 2; i++)
#pragma unroll
    for (int j = 0; j < 3; j++) acc[i][j] = zv;

  const int lr = lane & 15;
  const int kg = (lane >> 4) * 8;
  const int o0 = wave * 2048 + lane * 16;
  const int r0 = o0 >> 6, kb0 = o0 & 63;
  char* ldsA = (char*)As + wave * 2048;
  const int ob = wave * 1024 + lane * 16;
  const int rbn = ob >> 6, kbb = ob & 63;
  char* ldsB = (char*)Bs + wave * 1024;

  for (int k0 = 0; k0 < 1024; k0 += 32) {
    gload16(Ab + (size_t)r0 * 2048 + k0 * 2 + kb0, ldsA);
    gload16(Ab + (size_t)(r0 + 16) * 2048 + k0 * 2 + kb0, ldsA + 1024);
    if (wave < 3) gload16(Bb + (size_t)rbn * 2048 + k0 * 2 + kbb, ldsB);
    __syncthreads();
    short8 af[2], bfr[3];
#pragma unroll
    for (int mi = 0; mi < 2; mi++) af[mi] = *(const short8*)&As[(wave * 32 + mi * 16 + lr) * 32 + kg];
#pragma unroll
    for (int nf = 0; nf < 3; nf++) bfr[nf] = *(const short8*)&Bs[(nf * 16 + lr) * 32 + kg];
#pragma unroll
    for (int mi = 0; mi < 2; mi++)
#pragma unroll
      for (int nf = 0; nf < 3; nf++)
        acc[mi][nf] = __builtin_amdgcn_mfma_f32_16x16x32_bf16(af[mi], bfr[nf], acc[mi][nf], 0, 0, 0);
    __syncthreads();
  }

  const int rb = (lane >> 4) << 2;
#pragma unroll
  for (int mi = 0; mi < 2; mi++) {
#pragma unroll
    for (int nf = 0; nf < 3; nf++) {
      const int row0 = m0 + wave * 32 + mi * 16 + rb;  // 4-aligned; rows row0..row0+3 same batch
      const int b = row0 >> 10, s = row0 & 1023;
      const float c = cf[nf * 8 + b];
      f32x4 v = acc[mi][nf];
      float4 w;
      w.x = tanh_f(c * v[0]); w.y = tanh_f(c * v[1]);
      w.z = tanh_f(c * v[2]); w.w = tanh_f(c * v[3]);
      *(float4*)&U[(((size_t)nf * 8 + b) * 16 + lr) * 1024 + s] = w;
    }
  }
}

// ---------------- gated = x * Gsum ----------------
__global__ __launch_bounds__(256) void gate_combine(const u16* x, const u16* g, u16* outp) {
  size_t i = ((size_t)blockIdx.x * 256 + threadIdx.x) * 4;
  ushort4 xv = *(const ushort4*)(x + i);
  ushort4 a = *(const ushort4*)(g + i);
  ushort4 o;
  o.x = f2b(b2f(xv.x) * b2f(a.x));
  o.y = f2b(b2f(xv.y) * b2f(a.y));
  o.z = f2b(b2f(xv.z) * b2f(a.z));
  o.w = f2b(b2f(xv.w) * b2f(a.w));
  *(ushort4*)(outp + i) = o;
}

// ---------------- column sum (atomic partials) ----------------
__global__ __launch_bounds__(256) void colmean_at(const u16* X, float* Mo) {
  int b = blockIdx.y, g = blockIdx.x;
  int c = threadIdx.x * 4;
  const u16* p = X + (size_t)b * 1048576 + (size_t)g * 131072 + c;
  float s0 = 0, s1 = 0, s2 = 0, s3 = 0;
  for (int i = 0; i < 128; i++) {
    ushort4 v = *(const ushort4*)(p + (size_t)i * 1024);
    s0 += b2f(v.x); s1 += b2f(v.y); s2 += b2f(v.z); s3 += b2f(v.w);
  }
  float* o = Mo + b * 1024 + c;
  atomicAdd(o + 0, s0); atomicAdd(o + 1, s1); atomicAdd(o + 2, s2); atomicAdd(o + 3, s3);
}

// ---------------- tiny gate MLP (Mv holds column SUMS) ----------------
__global__ __launch_bounds__(256) void mlp2(const float* Mv, const u16* W1, const u16* b1,
                                            const u16* W2, const u16* b2, float* outv, int H) {
  int b = blockIdx.x, t = blockIdx.y, tid = threadIdx.x;
  __shared__ float mv[1024];
  __shared__ float red[256];
  for (int i = tid; i < 1024; i += 256) mv[i] = Mv[b * 1024 + i] * (1.f / 1024.f);
  __syncthreads();
  const u16* W1t = W1 + (size_t)t * 1024 * H;
  float a0 = 0.f, a1 = 0.f;
#pragma unroll 4
  for (int d = 0; d < 1024; d++) {
    float m = mv[d];
    a0 += m * b2f(W1t[(size_t)d * H + tid]);
    if (H > 256) a1 += m * b2f(W1t[(size_t)d * H + tid + 256]);
  }
  float acc;
  { float a = a0 + b2f(b1[t * H + tid]); acc = (a * sigmoid_f(a)) * b2f(W2[t * H + tid]); }
  if (H > 256) { float a = a1 + b2f(b1[t * H + tid + 256]); acc += (a * sigmoid_f(a)) * b2f(W2[t * H + tid + 256]); }
  red[tid] = acc;
  __syncthreads();
  for (int s = 128; s > 0; s >>= 1) { if (tid < s) red[tid] += red[tid + s]; __syncthreads(); }
  if (tid == 0) outv[t * 8 + b] = sigmoid_f(red[0] + b2f(b2[t]));
}

// ---------------- sequential scan with transposed-U prefetch ----------------
__global__ __launch_bounds__(64) void ssm_scan(const u16* Aw, const float* U, float* Ho) {
  int b = blockIdx.x, t = blockIdx.y, lane = threadIdx.x;
  int j = lane & 15, seg = lane >> 4;
  float a[4];
#pragma unroll
  for (int kk = 0; kk < 4; kk++) a[kk] = b2f(Aw[t * 256 + (seg * 4 + kk) * 16 + j]);
  const float* Uj = U + (((size_t)t * 8 + b) * 16 + j) * 1024;  // sequential in s
  float* Hr = Ho + ((size_t)t * 8192 + (size_t)b * 1024) * 16;
  float h = 0.f;
  float4 cur = *(const float4*)(Uj);
  float4 nxt = *(const float4*)(Uj + 4);
  for (int s0 = 0; s0 < 1024; s0 += 4) {
    float4 fut;
    if (s0 + 8 < 1024) fut = *(const float4*)(Uj + s0 + 8);
    else { fut.x = 0.f; fut.y = 0.f; fut.z = 0.f; fut.w = 0.f; }
    float uc0 = cur.x, uc1 = cur.y, uc2 = cur.z, uc3 = cur.w;
#pragma unroll
    for (int q = 0; q < 4; q++) {
      float part = 0.f;
#pragma unroll
      for (int kk = 0; kk < 4; kk++) part = fmaf(__shfl(h, seg * 4 + kk), a[kk], part);
      float xv = part + __shfl_xor(part, 16);
      xv += __shfl_xor(xv, 32);
      float uq = (q == 0) ? uc0 : (q == 1) ? uc1 : (q == 2) ? uc2 : uc3;
      h = tanh_fast(xv) + uq;
      if (lane < 16) Hr[(size_t)(s0 + q) * 16 + j] = h;
    }
    cur = nxt; nxt = fut;
  }
}

// ---------------- comb = sum_t tw[t]*(tanh(H@C[t]) + Dv[t]*cf*gated) ----------------
__global__ __launch_bounds__(256) void comb_k(const float* Hbuf, const u16* C, const u16* Dv,
                                              const float* cf, const u16* tsl, const u16* gated,
                                              u16* comb) {
  int r = blockIdx.x, tid = threadIdx.x;
  int b = r >> 10;
  __shared__ float Hs[3][16];
  __shared__ float tw[3];
  if (tid < 48) Hs[tid >> 4][tid & 15] = Hbuf[((size_t)(tid >> 4) * 8192 + r) * 16 + (tid & 15)];
  if (tid == 0) {
    float l0 = b2f(tsl[0]), l1 = b2f(tsl[1]), l2 = b2f(tsl[2]);
    float m = fmaxf(l0, fmaxf(l1, l2));
    float e0 = __expf(l0 - m), e1 = __expf(l1 - m), e2 = __expf(l2 - m);
    float s = e0 + e1 + e2;
    tw[0] = e0 / s; tw[1] = e1 / s; tw[2] = e2 / s;
  }
  __syncthreads();
  int d0 = tid * 4;
  ushort4 gv = *(const ushort4*)(gated + (size_t)r * 1024 + d0);
  float g0 = b2f(gv.x), g1 = b2f(gv.y), g2 = b2f(gv.z), g3v = b2f(gv.w);
  float o0 = 0, o1 = 0, o2 = 0, o3 = 0;
#pragma unroll
  for (int t = 0; t < 3; t++) {
    float w = tw[t], cfv = cf[t * 8 + b];
    float dA = 0, dB = 0, dC = 0, dD = 0;
#pragma unroll
    for (int k = 0; k < 16; k++) {
      float h = Hs[t][k];
      ushort4 cv = *(const ushort4*)(C + ((size_t)t * 16 + k) * 1024 + d0);
      dA += h * b2f(cv.x); dB += h * b2f(cv.y); dC += h * b2f(cv.z); dD += h * b2f(cv.w);
    }
    float dvw = w * cfv;
    o0 += w * tanh_f(dA) + dvw * b2f(Dv[t * 1024 + d0 + 0]) * g0;
    o1 += w * tanh_f(dB) + dvw * b2f(Dv[t * 1024 + d0 + 1]) * g1;
    o2 += w * tanh_f(dC) + dvw * b2f(Dv[t * 1024 + d0 + 2]) * g2;
    o3 += w * tanh_f(dD) + dvw * b2f(Dv[t * 1024 + d0 + 3]) * g3v;
  }
  ushort4 ov;
  ov.x = f2b(o0); ov.y = f2b(o1); ov.z = f2b(o2); ov.w = f2b(o3);
  *(ushort4*)(comb + (size_t)r * 1024 + d0) = ov;
}

// ---------------- row softmax, IN PLACE ----------------
__global__ __launch_bounds__(256) void softmax_row(float* S) {
  int r = blockIdx.x, tid = threadIdx.x;
  float* row = S + (size_t)r * 1024;
  float4 v = ((const float4*)row)[tid];
  float mx = fmaxf(fmaxf(v.x, v.y), fmaxf(v.z, v.w));
  for (int o = 32; o; o >>= 1) mx = fmaxf(mx, __shfl_xor(mx, o));
  __shared__ float sm[4], ssum[4];
  int ln = tid & 63, wv = tid >> 6;
  if (!ln) sm[wv] = mx;
  __syncthreads();
  mx = fmaxf(fmaxf(sm[0], sm[1]), fmaxf(sm[2], sm[3]));
  float e0 = __expf(v.x - mx), e1 = __expf(v.y - mx), e2 = __expf(v.z - mx), e3 = __expf(v.w - mx);
  float s = e0 + e1 + e2 + e3;
  for (int o = 32; o; o >>= 1) s += __shfl_xor(s, o);
  if (!ln) ssum[wv] = s;
  __syncthreads();
  s = ssum[0] + ssum[1] + ssum[2] + ssum[3];
  float inv = 1.f / s;
  ushort4 pk;
  pk.x = f2b(e0 * inv); pk.y = f2b(e1 * inv); pk.z = f2b(e2 * inv); pk.w = f2b(e3 * inv);
  __syncthreads();
  ((ushort4*)row)[tid] = pk;
}

// ---------------- comp = mem_gated*cpf ; layernorm ----------------
__global__ __launch_bounds__(256) void ln_k(const u16* MG, const float* cpf, const u16* lng,
                                            const u16* lnb, u16* outp) {
  int r = blockIdx.x, tid = threadIdx.x;
  float cfv = cpf[r >> 10];
  ushort4 m4 = *(const ushort4*)(MG + (size_t)r * 1024 + tid * 4);
  float c0 = b2f(m4.x) * cfv, c1 = b2f(m4.y) * cfv, c2 = b2f(m4.z) * cfv, c3 = b2f(m4.w) * cfv;
  float s = c0 + c1 + c2 + c3;
  float q = c0 * c0 + c1 * c1 + c2 * c2 + c3 * c3;
  int ln = tid & 63, wv = tid >> 6;
  for (int o = 32; o; o >>= 1) { s += __shfl_xor(s, o); q += __shfl_xor(q, o); }
  __shared__ float ss[4], qq[4];
  if (!ln) { ss[wv] = s; qq[wv] = q; }
  __syncthreads();
  s = ss[0] + ss[1] + ss[2] + ss[3];
  q = qq[0] + qq[1] + qq[2] + qq[3];
  float mu = s * (1.f / 1024.f);
  float var = q * (1.f / 1024.f) - mu * mu;
  float inv = rsqrtf(fmaxf(var, 0.f) + 1e-5f);
  int d = tid * 4;
  ushort4 ov;
  ov.x = f2b((c0 - mu) * inv * b2f(lng[d + 0]) + b2f(lnb[d + 0]));
  ov.y = f2b((c1 - mu) * inv * b2f(lng[d + 1]) + b2f(lnb[d + 1]));
  ov.z = f2b((c2 - mu) * inv * b2f(lng[d + 2]) + b2f(lnb[d + 2]));
  ov.w = f2b((c3 - mu) * inv * b2f(lng[d + 3]) + b2f(lnb[d + 3]));
  *(ushort4*)(outp + (size_t)r * 1024 + d) = ov;
}

// =================================================================================
extern "C" void kernel_launch(void* const* d_in, const int* in_sizes, int n_in,
                              void* d_out, int out_size, void* d_ws, size_t ws_size,
                              hipStream_t stream) {
  (void)in_sizes; (void)n_in; (void)out_size; (void)ws_size;
  const void* x = d_in[0];
  const void* mask = d_in[1];
  const void* tsl = d_in[2];
  const void* gw1 = d_in[3];
  const void* gb1 = d_in[4];
  const void* gw2 = d_in[5];
  const void* gb2 = d_in[6];
  const void* gwts = d_in[7];
  const void* ssmA = d_in[8];
  const void* ssmBm = d_in[9];
  const void* ssmC = d_in[10];
  const void* ssmD = d_in[11];
  const void* cgw1 = d_in[12];
  const void* cgb1 = d_in[13];
  const void* cgw2 = d_in[14];
  const void* cgb2 = d_in[15];
  const void* wq = d_in[16]; const void* bq = d_in[17];
  const void* wk = d_in[18]; const void* bk = d_in[19];
  const void* wv = d_in[20]; const void* bvp = d_in[21];
  const void* wo = d_in[22]; const void* bo = d_in[23];
  const void* mgate = d_in[24];
  const void* cpw1 = d_in[25];
  const void* cpb1 = d_in[26];
  const void* cpw2 = d_in[27];
  const void* cpb2 = d_in[28];
  const void* lng = d_in[29];
  const void* lnb = d_in[30];
  const void* outw = d_in[31];
  const void* outb = d_in[32];

  // ---- workspace layout (~104 MB) ----
  char* ws = (char*)d_ws;
  const size_t MBe = 1048576;
  u16* W = (u16*)ws;                       // 6 x 2MB transposed-weight slots
  char* S1 = ws + 12582912;                // 16 MB : T1[0] -> Q -> attnT
  char* S2 = S1 + 16777216;                // 16 MB : T1[1] -> gated -> K -> normed
  char* S3 = S2 + 16777216;                // 16 MB : T1[2] -> comb
  char* SC = S3 + 16777216;                // 32 MB : xb (lo) + Gsum (hi) -> scores f32
  u16* xb = (u16*)SC;                      // bf16 x in SC lower half
  char* SChi = SC + 16777216;              // Gsum accumulator
  u8* maskb = (u8*)(SC + 33554432);        // 8 MB
  u16* SM = (u16*)(maskb + 8388608);       // small converted arrays
  char* S4 = (char*)d_out;                 // scratch: Vt -> mem_gated (overwritten by final GEMM)

  size_t off = 0;
  auto alloc = [&](size_t n) { u16* p = SM + off; off += (n + 7) & ~(size_t)7; return p; };
  u16* c_gb1 = alloc(3072);  u16* c_gb2 = alloc(3072);
  u16* c_gwts = alloc(3);    u16* c_tsl = alloc(3);
  u16* c_ssmA = alloc(768);  u16* c_ssmBm = alloc(49152);
  u16* c_ssmC = alloc(49152); u16* c_ssmD = alloc(3072);
  u16* c_cgw1 = alloc(786432); u16* c_cgb1 = alloc(768);
  u16* c_cgw2 = alloc(768);  u16* c_cgb2 = alloc(3);
  u16* c_bq = alloc(1024);   u16* c_bk = alloc(1024);
  u16* c_bv = alloc(1024);   u16* c_bo = alloc(1024);
  u16* c_mg = alloc(1024);   u16* c_cpw1 = alloc(524288);
  u16* c_cpb1 = alloc(512);  u16* c_cpw2 = alloc(512);
  u16* c_cpb2 = alloc(1);    u16* c_lng = alloc(1024);
  u16* c_lnb = alloc(1024);  u16* c_outb = alloc(1024);
  u16* BmT = alloc(49152);
  char* tail = (char*)(SM + ((off + 7) & ~(size_t)7));
  float* Ubuf = (float*)tail;       // [t][b][j][s] = 3*8*16*1024 f32
  float* Hbuf = Ubuf + 393216;      // [t][r][j]
  float* Mf = Hbuf + 393216;
  float* Mcf = Mf + 8192;
  float* cff = Mcf + 8192;
  float* cpf = cff + 32;
  u32* flags = (u32*)(cpf + 8);

  // 0. detect dtypes; zero atomic accumulators
  detect_k<<<1, 256, 0, stream>>>((const u32*)mgate, (const u32*)mask, flags);
  zero_f<<<64, 256, 0, stream>>>(Mf, 16384);

  // 1. convert all small arrays + x
  {
    CvtTab tb{};
    const void* srcs[NCVT] = {gb1, gb2, gwts, tsl, ssmA, ssmBm, ssmC, ssmD, cgw1, cgb1, cgw2, cgb2,
                              bq, bk, bvp, bo, mgate, cpw1, cpb1, cpw2, cpb2, lng, lnb, outb, x};
    u16* dsts[NCVT] = {c_gb1, c_gb2, c_gwts, c_tsl, c_ssmA, c_ssmBm, c_ssmC, c_ssmD, c_cgw1, c_cgb1,
                       c_cgw2, c_cgb2, c_bq, c_bk, c_bv, c_bo, c_mg, c_cpw1, c_cpb1, c_cpw2, c_cpb2,
                       c_lng, c_lnb, c_outb, xb};
    int ns[NCVT] = {3072, 3072, 3, 3, 768, 49152, 49152, 3072, 786432, 768, 768, 3,
                    1024, 1024, 1024, 1024, 1024, 524288, 512, 512, 1, 1024, 1024, 1024, 8388608};
    for (int i = 0; i < NCVT; i++) { tb.src[i] = srcs[i]; tb.dst[i] = dsts[i]; tb.n[i] = ns[i]; }
    cvt_table<<<dim3(256, NCVT), 256, 0, stream>>>(tb, flags);
  }

  // 2. mask -> u8 ; BmT
  cvt_mask<<<8192, 256, 0, stream>>>(mask, (u32*)maskb, flags);
  bmt_k<<<48, 256, 0, stream>>>(c_ssmBm, BmT);

  // 3. convert+transpose gw1 x3, gw2 x3
  {
    TPC tp{};
    for (int i = 0; i < 3; i++) { tp.src[i] = gw1; tp.soff[i] = (long)i * MBe; tp.dst[i] = W + (size_t)i * MBe; }
    for (int i = 0; i < 3; i++) { tp.src[3 + i] = gw2; tp.soff[3 + i] = (long)i * MBe; tp.dst[3 + i] = W + (size_t)(3 + i) * MBe; }
    transpose_cvt<<<dim3(16, 16, 6), dim3(64, 4), 0, stream>>>(tp, flags);
  }

  // 4. T1[i] = silu(xb @ gw1t[i] + gb1[i]), z-batched -> S1,S2,S3 (1536 blocks)
  { GemmP p; p.A = xb; p.Bt = W; p.C = S1; p.sAz = 0; p.sBz = (long)MBe; p.sCzB = 16777216;
    p.lda = 1024; p.ldb = 1024; p.ldc = 1024; p.K = 1024;
    Ep e{}; e.bias = c_gb1;
    gemm_bt<0><<<dim3(8, 64, 3), 512, 0, stream>>>(p, e); }

  // 5. Gsum (+)= gweights[i]*sigmoid(T1[i] @ gw2t[i] + gb2[i]) -> SChi
  for (int i = 0; i < 3; i++) {
    GemmP p; p.A = (u16*)(S1 + (size_t)i * 16777216); p.Bt = W + (size_t)(3 + i) * MBe; p.C = SChi;
    p.sAz = 0; p.sBz = 0; p.sCzB = 0;
    p.lda = 1024; p.ldb = 1024; p.ldc = 1024; p.K = 1024;
    Ep e{}; e.bias = c_gb2 + i * 1024; e.gw = c_gwts + i; e.accum = i;
    gemm_bt<1><<<dim3(8, 64, 1), 512, 0, stream>>>(p, e);
  }

  // 6. gated = x * Gsum -> S2
  gate_combine<<<8192, 256, 0, stream>>>(xb, (u16*)SChi, (u16*)S2);

  // 7. context gates
  colmean_at<<<dim3(8, 8), 256, 0, stream>>>((u16*)S2, Mf);
  mlp2<<<dim3(8, 3), 256, 0, stream>>>(Mf, c_cgw1, c_cgb1, c_cgw2, c_cgb2, cff, 256);

  // 8. U (transposed layout) then scan
  ssm_u_mfma<<<64, 256, 0, stream>>>((u16*)S2, BmT, cff, Ubuf);
  ssm_scan<<<dim3(8, 3), 64, 0, stream>>>(c_ssmA, Ubuf, Hbuf);

  // 9. comb -> S3
  comb_k<<<8192, 256, 0, stream>>>(Hbuf, c_ssmC, c_ssmD, cff, c_tsl, (u16*)S2, (u16*)S3);

  // 10. convert+transpose wq,wk,wv
  {
    TPC tp{};
    tp.src[0] = wq; tp.soff[0] = 0; tp.dst[0] = W;
    tp.src[1] = wk; tp.soff[1] = 0; tp.dst[1] = W + MBe;
    tp.src[2] = wv; tp.soff[2] = 0; tp.dst[2] = W + 2 * MBe;
    transpose_cvt<<<dim3(16, 16, 3), dim3(64, 4), 0, stream>>>(tp, flags);
  }

  // 11. Q->S1, K->S2, Vt->S4(d_out)
  { GemmP p; p.A = (u16*)S3; p.Bt = W; p.C = S1; p.sAz = 0; p.sBz = (long)MBe; p.sCzB = 0;
    p.lda = 1024; p.ldb = 1024; p.ldc = 1024; p.K = 1024;
    Ep e{}; e.bias = c_bq; e.bias1 = c_bk; e.bias2 = c_bv; e.cQ = S1; e.cK = S2; e.cV = S4;
    gemm_bt<2><<<dim3(8, 64, 3), 512, 0, stream>>>(p, e); }

  // 12. masked scores (f32) -> SC
  { GemmP p; p.A = (u16*)S1; p.Bt = (u16*)S2; p.C = SC; p.sAz = (long)MBe; p.sBz = (long)MBe;
    p.sCzB = 4194304; p.lda = 1024; p.ldb = 1024; p.ldc = 1024; p.K = 1024;
    Ep e{}; e.mask8 = maskb; e.scale = 0.03125f;
    gemm_bt<3><<<dim3(8, 8, 8), 512, 0, stream>>>(p, e); }

  // 13. softmax in place
  softmax_row<<<8192, 256, 0, stream>>>((float*)SC);

  // 14. attnT = (probs @ V)^T per batch -> S1
  { GemmP p; p.A = (u16*)SC; p.Bt = (u16*)S4; p.C = S1; p.sAz = 2097152; p.sBz = (long)MBe;
    p.sCzB = 2097152; p.lda = 2048; p.ldb = 1024; p.ldc = 1024; p.K = 1024;
    Ep e{};
    gemm_bt<4><<<dim3(8, 8, 8), 512, 0, stream>>>(p, e); }

  // 15. convert+transpose wo, out_w
  {
    TPC tp{};
    tp.src[0] = wo; tp.soff[0] = 0; tp.dst[0] = W;
    tp.src[1] = outw; tp.soff[1] = 0; tp.dst[1] = W + MBe;
    transpose_cvt<<<dim3(16, 16, 2), dim3(64, 4), 0, stream>>>(tp, flags);
  }

  // 16. mem_gated = (attnT @ wo + bo) * comb * mem_gate -> S4(d_out)
  { GemmP p; p.A = (u16*)S1; p.Bt = W; p.C = S4; p.sAz = 0; p.sBz = 0; p.sCzB = 0;
    p.lda = 1024; p.ldb = 1024; p.ldc = 1024; p.K = 1024;
    Ep e{}; e.bias = c_bo; e.comb = (u16*)S3; e.mgate = c_mg;
    gemm_bt<5><<<dim3(8, 64, 1), 512, 0, stream>>>(p, e); }

  // 17. compression gate
  colmean_at<<<dim3(8, 8), 256, 0, stream>>>((u16*)S4, Mcf);
  mlp2<<<dim3(8, 1), 256, 0, stream>>>(Mcf, c_cpw1, c_cpb1, c_cpw2, c_cpb2, cpf, 512);

  // 18. scale + layernorm -> normed -> S2
  ln_k<<<8192, 256, 0, stream>>>((u16*)S4, cpf, c_lng, c_lnb, (u16*)S2);

  // 19. out = normed @ out_w + out_b -> d_out (dtype per flags)
  { GemmP p; p.A = (u16*)S2; p.Bt = W + MBe; p.C = (char*)d_out; p.sAz = 0; p.sBz = 0; p.sCzB = 0;
    p.lda = 1024; p.ldb = 1024; p.ldc = 1024; p.K = 1024;
    Ep e{}; e.bias = c_outb; e.flags = flags;
    gemm_bt<6><<<dim3(8, 64, 1), 512, 0, stream>>>(p, e); }
}

// Round 6
// 943.914 us; speedup vs baseline: 1.6148x; 1.3429x over previous
//
#include <hip/hip_runtime.h>

#define DEVINL __device__ __forceinline__

typedef unsigned short u16;
typedef unsigned int u32;
typedef unsigned char u8;
typedef __attribute__((ext_vector_type(8))) short short8;
typedef __attribute__((ext_vector_type(4))) float f32x4;

// ---------------- numeric helpers ----------------
DEVINL float b2f(u16 u) { union { u32 u; float f; } v; v.u = ((u32)u) << 16; return v.f; }
DEVINL u16 f2b(float f) {
  union { float f; u32 u; } v; v.f = f;
  u32 u = v.u;
  return (u16)((u + 0x7FFFu + ((u >> 16) & 1u)) >> 16);  // RNE
}
DEVINL float sigmoid_f(float x) { float c = fminf(fmaxf(x, -30.f), 30.f); return 1.f / (1.f + __expf(-c)); }
DEVINL float tanh_f(float x) { float c = fminf(fmaxf(x, -15.f), 15.f); float e = __expf(2.f * c); return (e - 1.f) / (e + 1.f); }
DEVINL float tanh_fast(float x) {
  float c = fminf(fmaxf(x, -15.f), 15.f);
  float e = __expf(2.f * c);
  return 1.f - 2.f * __builtin_amdgcn_rcpf(e + 1.f);
}

DEVINL void gload16(const void* g, void* l) {
  __builtin_amdgcn_global_load_lds((const __attribute__((address_space(1))) void*)g,
                                   (__attribute__((address_space(3))) void*)l, 16, 0, 0);
}

// ---------------- dtype detection ----------------
__global__ void detect_k(const u32* mg, const u32* mask, u32* flags) {
  __shared__ int any8;
  if (threadIdx.x == 0) any8 = 0;
  __syncthreads();
  for (int i = threadIdx.x; i < 4096; i += 256) { if (mask[i] > 1u) any8 = 1; }
  __syncthreads();
  if (threadIdx.x == 0) {
    flags[0] = (mg[0] == 0x3F800000u) ? 1u : 0u;
    flags[1] = any8 ? 1u : 0u;
  }
}

// ---------------- zero floats ----------------
__global__ __launch_bounds__(256) void zero_f(float* p, int n) {
  int i = blockIdx.x * 256 + threadIdx.x;
  if (i < n) p[i] = 0.f;
}

// ---------------- table-driven convert (f32->bf16 or bf16 copy) ----------------
#define NCVT 25
struct CvtTab { const void* src[NCVT]; u16* dst[NCVT]; int n[NCVT]; };

__global__ __launch_bounds__(256) void cvt_table(CvtTab tb, const u32* flags) {
  int e = blockIdx.y;
  int n = tb.n[e];
  int idx = blockIdx.x * 256 + threadIdx.x, step = gridDim.x * 256;
  if (flags[0]) {
    const float* s = (const float*)tb.src[e]; u16* d = tb.dst[e];
    for (int i = idx; i < n; i += step) d[i] = f2b(s[i]);
  } else {
    const u16* s = (const u16*)tb.src[e]; u16* d = tb.dst[e];
    for (int i = idx; i < n; i += step) d[i] = s[i];
  }
}

// ---------------- mask -> u8 (0/1) ----------------
__global__ __launch_bounds__(256) void cvt_mask(const void* src, u32* dst, const u32* flags) {
  size_t i = (size_t)blockIdx.x * 256 + threadIdx.x;
  if (flags[1]) {
    dst[i] = ((const u32*)src)[i];
  } else {
    int4 w = ((const int4*)src)[i];
    dst[i] = (w.x ? 1u : 0u) | ((w.y ? 1u : 0u) << 8) | ((w.z ? 1u : 0u) << 16) | ((w.w ? 1u : 0u) << 24);
  }
}

// ---------------- fused convert + transpose (up to 6 square 1024x1024 mats) ----------------
struct TPC { const void* src[6]; u16* dst[6]; long soff[6]; };

__global__ __launch_bounds__(256) void transpose_cvt(TPC p, const u32* flags) {
  __shared__ u16 t[64][65];
  int z = blockIdx.z, tx = threadIdx.x;
  int x0 = blockIdx.x * 64, y0 = blockIdx.y * 64;
  if (flags[0]) {
    const float* s = (const float*)p.src[z] + p.soff[z];
    for (int i = threadIdx.y; i < 64; i += 4) t[i][tx] = f2b(s[(size_t)(y0 + i) * 1024 + x0 + tx]);
  } else {
    const u16* s = (const u16*)p.src[z] + p.soff[z];
    for (int i = threadIdx.y; i < 64; i += 4) t[i][tx] = s[(size_t)(y0 + i) * 1024 + x0 + tx];
  }
  __syncthreads();
  u16* d = p.dst[z];
  for (int i = threadIdx.y; i < 64; i += 4) d[(size_t)(x0 + i) * 1024 + y0 + tx] = t[tx][i];
}

// ---------------- Bm[t][1024][16] -> BmT[48][1024] ----------------
__global__ __launch_bounds__(256) void bmt_k(const u16* Bm, u16* BmT) {
  int n = blockIdx.x, t = n >> 4, j = n & 15;
  for (int d = threadIdx.x; d < 1024; d += 256)
    BmT[(size_t)n * 1024 + d] = Bm[(size_t)t * 16384 + (size_t)d * 16 + j];
}

// ---------------- 128x128 MFMA GEMM, 512 threads (8 waves: 4m x 2n), B TRANSPOSED ----------------
struct GemmP {
  const u16* A; const u16* Bt; char* C;
  long sAz, sBz;
  size_t sCzB;
  int lda, ldb, ldc, K;
};
struct Ep {
  const u16 *bias, *bias1, *bias2, *comb, *mgate, *gw;
  const u8* mask8;
  const u32* flags;
  char *cQ, *cK, *cV;
  float scale;
  int accum;
};

template <int MODE>
__global__ __launch_bounds__(512, 4) void gemm_bt(GemmP p, Ep ep) {
  __shared__ u16 As[128 * 32];
  __shared__ u16 Bs[128 * 32];
  const int tid = threadIdx.x;
  const int lane = tid & 63, wave = tid >> 6;   // 0..7
  const int wm = wave & 3, wn = wave >> 2;      // 4 m-groups x 2 n-groups
  const int z = blockIdx.z;
  const int m0 = blockIdx.y * 128, n0 = blockIdx.x * 128;

  const char* Ab = (const char*)p.A + ((size_t)z * p.sAz + (size_t)m0 * p.lda) * 2;
  const char* Bb = (const char*)p.Bt + ((size_t)z * p.sBz + (size_t)n0 * p.ldb) * 2;

  f32x4 acc[2][4];
  const f32x4 zv = {0.f, 0.f, 0.f, 0.f};
#pragma unroll
  for (int i = 0; i < 2; i++)
#pragma unroll
    for (int j = 0; j < 4; j++) acc[i][j] = zv;

  const int lr = lane & 15;
  const int kg = (lane >> 4) * 8;
  const int ldaB = p.lda * 2, ldbB = p.ldb * 2;

  const int o0 = tid * 16;
  const int r0 = o0 >> 6, kb0 = o0 & 63;
  char* ldsA = (char*)As + wave * 1024;
  char* ldsB = (char*)Bs + wave * 1024;

  for (int k0 = 0; k0 < p.K; k0 += 32) {
    gload16(Ab + (size_t)r0 * ldaB + k0 * 2 + kb0, ldsA);
    gload16(Bb + (size_t)r0 * ldbB + k0 * 2 + kb0, ldsB);
    __syncthreads();
    short8 af[2], bfr[4];
#pragma unroll
    for (int mi = 0; mi < 2; mi++) af[mi] = *(const short8*)&As[(wm * 32 + mi * 16 + lr) * 32 + kg];
#pragma unroll
    for (int ni = 0; ni < 4; ni++) bfr[ni] = *(const short8*)&Bs[(wn * 64 + ni * 16 + lr) * 32 + kg];
#pragma unroll
    for (int mi = 0; mi < 2; mi++)
#pragma unroll
      for (int ni = 0; ni < 4; ni++)
        acc[mi][ni] = __builtin_amdgcn_mfma_f32_16x16x32_bf16(af[mi], bfr[ni], acc[mi][ni], 0, 0, 0);
    __syncthreads();
  }

  char* Cb = p.C + (size_t)z * p.sCzB;
  const int rb = (lane >> 4) << 2;
#pragma unroll
  for (int mi = 0; mi < 2; mi++) {
#pragma unroll
    for (int ni = 0; ni < 4; ni++) {
      const int row0 = m0 + wm * 32 + mi * 16 + rb;
      const int col = n0 + wn * 64 + ni * 16 + lr;
      f32x4 v = acc[mi][ni];
      if constexpr (MODE == 0) {           // T1 = silu(acc + gb1[z]), z-batched
        float bv = b2f(ep.bias[z * 1024 + col]);
        u16* C = (u16*)Cb;
#pragma unroll
        for (int j = 0; j < 4; j++) { float a = v[j] + bv; C[(size_t)(row0 + j) * p.ldc + col] = f2b(a * sigmoid_f(a)); }
      } else if constexpr (MODE == 1) {    // Gsum (+)= gw*sigmoid(acc+bias)
        float bv = b2f(ep.bias[col]);
        float w = b2f(ep.gw[0]);
        u16* C = (u16*)Cb;
#pragma unroll
        for (int j = 0; j < 4; j++) {
          size_t idx = (size_t)(row0 + j) * p.ldc + col;
          float t = w * sigmoid_f(v[j] + bv);
          if (ep.accum) t += b2f(C[idx]);
          C[idx] = f2b(t);
        }
      } else if constexpr (MODE == 2) {    // QKV; z==2 -> transposed V store
        const u16* bp = (z == 0) ? ep.bias : ((z == 1) ? ep.bias1 : ep.bias2);
        float bv = b2f(bp[col]);
        if (z == 0) {
          u16* C = (u16*)ep.cQ;
#pragma unroll
          for (int j = 0; j < 4; j++) C[(size_t)(row0 + j) * p.ldc + col] = f2b(v[j] + bv);
        } else if (z == 1) {
          u16* C = (u16*)ep.cK;
#pragma unroll
          for (int j = 0; j < 4; j++) C[(size_t)(row0 + j) * p.ldc + col] = f2b(v[j] + bv);
        } else {
          int b = row0 >> 10, s = row0 & 1023;
          ushort4 pk;
          pk.x = f2b(v[0] + bv); pk.y = f2b(v[1] + bv); pk.z = f2b(v[2] + bv); pk.w = f2b(v[3] + bv);
          *(ushort4*)((u16*)ep.cV + (size_t)b * 1048576 + (size_t)col * 1024 + s) = pk;
        }
      } else if constexpr (MODE == 3) {    // masked scores f32
        float* C = (float*)Cb;
        const u8* mrow = ep.mask8 + (size_t)z * 1048576;
#pragma unroll
        for (int j = 0; j < 4; j++) {
          float sc = v[j] * ep.scale;
          C[(size_t)(row0 + j) * p.ldc + col] = mrow[(size_t)(row0 + j) * 1024 + col] ? sc : -1e30f;
        }
      } else if constexpr (MODE == 4) {    // PV transposed store
        ushort4 pk;
        pk.x = f2b(v[0]); pk.y = f2b(v[1]); pk.z = f2b(v[2]); pk.w = f2b(v[3]);
        *(ushort4*)((u16*)Cb + (size_t)col * 1024 + row0) = pk;
      } else if constexpr (MODE == 5) {    // mem_gated
        float bv = b2f(ep.bias[col]);
        float mg = b2f(ep.mgate[col]);
        u16* C = (u16*)Cb;
#pragma unroll
        for (int j = 0; j < 4; j++) {
          size_t idx = (size_t)(row0 + j) * p.ldc + col;
          C[idx] = f2b((v[j] + bv) * b2f(ep.comb[idx]) * mg);
        }
      } else {  // MODE 6: final out, dtype per flags
        float bv = b2f(ep.bias[col]);
        if (ep.flags[0]) {
          float* C = (float*)Cb;
#pragma unroll
          for (int j = 0; j < 4; j++) C[(size_t)(row0 + j) * p.ldc + col] = v[j] + bv;
        } else {
          u16* C = (u16*)Cb;
#pragma unroll
          for (int j = 0; j < 4; j++) C[(size_t)(row0 + j) * p.ldc + col] = f2b(v[j] + bv);
        }
      }
    }
  }
}

// ---------------- ssm_u: skinny MFMA, writes U TRANSPOSED [t][b][j][s] f32 ----------------
__global__ __launch_bounds__(256, 2) void ssm_u_mfma(const u16* A, const u16* BmT,
                                                     const float* cf, float* U) {
  __shared__ u16 As[128 * 32];
  __shared__ u16 Bs[48 * 32];
  const int tid = threadIdx.x;
  const int lane = tid & 63, wave = tid >> 6;
  const int m0 = blockIdx.x * 128;
  const char* Ab = (const char*)A + (size_t)m0 * 2048;
  const char* Bb = (const char*)BmT;

  f32x4 acc[2][3];
  const f32x4 zv = {0.f, 0.f, 0.f, 0.f};
#pragma unroll
  for (int i = 0; i < 2; i++)
#pragma unroll
    for (int j = 0; j < 3; j++) acc[i][j] = zv;

  const int lr = lane & 15;
  const int kg = (lane >> 4) * 8;
  const int o0 = wave * 2048 + lane * 16;
  const int r0 = o0 >> 6, kb0 = o0 & 63;
  char* ldsA = (char*)As + wave * 2048;
  const int ob = wave * 1024 + lane * 16;
  const int rbn = ob >> 6, kbb = ob & 63;
  char* ldsB = (char*)Bs + wave * 1024;

  for (int k0 = 0; k0 < 1024; k0 += 32) {
    gload16(Ab + (size_t)r0 * 2048 + k0 * 2 + kb0, ldsA);
    gload16(Ab + (size_t)(r0 + 16) * 2048 + k0 * 2 + kb0, ldsA + 1024);
    if (wave < 3) gload16(Bb + (size_t)rbn * 2048 + k0 * 2 + kbb, ldsB);
    __syncthreads();
    short8 af[2], bfr[3];
#pragma unroll
    for (int mi = 0; mi < 2; mi++) af[mi] = *(const short8*)&As[(wave * 32 + mi * 16 + lr) * 32 + kg];
#pragma unroll
    for (int nf = 0; nf < 3; nf++) bfr[nf] = *(const short8*)&Bs[(nf * 16 + lr) * 32 + kg];
#pragma unroll
    for (int mi = 0; mi < 2; mi++)
#pragma unroll
      for (int nf = 0; nf < 3; nf++)
        acc[mi][nf] = __builtin_amdgcn_mfma_f32_16x16x32_bf16(af[mi], bfr[nf], acc[mi][nf], 0, 0, 0);
    __syncthreads();
  }

  const int rb = (lane >> 4) << 2;
#pragma unroll
  for (int mi = 0; mi < 2; mi++) {
#pragma unroll
    for (int nf = 0; nf < 3; nf++) {
      const int row0 = m0 + wave * 32 + mi * 16 + rb;
      const int b = row0 >> 10, s = row0 & 1023;
      const float c = cf[nf * 8 + b];
      f32x4 v = acc[mi][nf];
      float4 w;
      w.x = tanh_f(c * v[0]); w.y = tanh_f(c * v[1]);
      w.z = tanh_f(c * v[2]); w.w = tanh_f(c * v[3]);
      *(float4*)&U[(((size_t)nf * 8 + b) * 16 + lr) * 1024 + s] = w;
    }
  }
}

// ---------------- gated = x * Gsum ----------------
__global__ __launch_bounds__(256) void gate_combine(const u16* x, const u16* g, u16* outp) {
  size_t i = ((size_t)blockIdx.x * 256 + threadIdx.x) * 4;
  ushort4 xv = *(const ushort4*)(x + i);
  ushort4 a = *(const ushort4*)(g + i);
  ushort4 o;
  o.x = f2b(b2f(xv.x) * b2f(a.x));
  o.y = f2b(b2f(xv.y) * b2f(a.y));
  o.z = f2b(b2f(xv.z) * b2f(a.z));
  o.w = f2b(b2f(xv.w) * b2f(a.w));
  *(ushort4*)(outp + i) = o;
}

// ---------------- column sum (atomic partials), 32 rows per block ----------------
__global__ __launch_bounds__(256) void colmean_at(const u16* X, float* Mo) {
  int b = blockIdx.y, g = blockIdx.x;
  int c = threadIdx.x * 4;
  const u16* p = X + (size_t)b * 1048576 + (size_t)g * 32768 + c;
  float s0 = 0, s1 = 0, s2 = 0, s3 = 0;
  for (int i = 0; i < 32; i++) {
    ushort4 v = *(const ushort4*)(p + (size_t)i * 1024);
    s0 += b2f(v.x); s1 += b2f(v.y); s2 += b2f(v.z); s3 += b2f(v.w);
  }
  float* o = Mo + b * 1024 + c;
  atomicAdd(o + 0, s0); atomicAdd(o + 1, s1); atomicAdd(o + 2, s2); atomicAdd(o + 3, s3);
}

// ---------------- tiny MLP stage 1: acc[t][b][j] += sum_{d in chunk} mv[d]*W1[d][j] ----------------
// grid (B=8, T, 16 d-chunks of 64); Mv holds column SUMS (scaled by 1/1024 here)
__global__ __launch_bounds__(256) void mlp_s1(const float* Mv, const u16* W1, float* acc, int H) {
  int b = blockIdx.x, t = blockIdx.y, dch = blockIdx.z;
  int tx = threadIdx.x & 63, ty = threadIdx.x >> 6;  // ty 0..3
  const u16* W1t = W1 + (size_t)t * 1024 * H;
  for (int cb = 0; cb < H; cb += 256) {
    int c = cb + tx * 4;
    float a0 = 0, a1 = 0, a2 = 0, a3 = 0;
    for (int i = ty; i < 64; i += 4) {
      int d = dch * 64 + i;
      float m = Mv[b * 1024 + d] * (1.f / 1024.f);
      ushort4 w = *(const ushort4*)(W1t + (size_t)d * H + c);
      a0 = fmaf(m, b2f(w.x), a0); a1 = fmaf(m, b2f(w.y), a1);
      a2 = fmaf(m, b2f(w.z), a2); a3 = fmaf(m, b2f(w.w), a3);
    }
    float* o = acc + ((size_t)t * 8 + b) * H + c;
    atomicAdd(o + 0, a0); atomicAdd(o + 1, a1); atomicAdd(o + 2, a2); atomicAdd(o + 3, a3);
  }
}

// ---------------- tiny MLP stage 2: out[t*8+b] = sigmoid(sum_j silu(acc+b1)*W2 + b2) ----------------
__global__ __launch_bounds__(256) void mlp_s2(const float* acc, const u16* b1, const u16* W2,
                                              const u16* b2, float* outv, int H) {
  int b = blockIdx.x, t = blockIdx.y, tid = threadIdx.x;
  float s = 0.f;
  for (int j = tid; j < H; j += 256) {
    float a = acc[((size_t)t * 8 + b) * H + j] + b2f(b1[t * H + j]);
    s += (a * sigmoid_f(a)) * b2f(W2[t * H + j]);
  }
  __shared__ float red[256];
  red[tid] = s;
  __syncthreads();
  for (int k = 128; k > 0; k >>= 1) { if (tid < k) red[tid] += red[tid + k]; __syncthreads(); }
  if (tid == 0) outv[t * 8 + b] = sigmoid_f(red[0] + b2f(b2[t]));
}

// ---------------- sequential scan with transposed-U prefetch ----------------
__global__ __launch_bounds__(64) void ssm_scan(const u16* Aw, const float* U, float* Ho) {
  int b = blockIdx.x, t = blockIdx.y, lane = threadIdx.x;
  int j = lane & 15, seg = lane >> 4;
  float a[4];
#pragma unroll
  for (int kk = 0; kk < 4; kk++) a[kk] = b2f(Aw[t * 256 + (seg * 4 + kk) * 16 + j]);
  const float* Uj = U + (((size_t)t * 8 + b) * 16 + j) * 1024;
  float* Hr = Ho + ((size_t)t * 8192 + (size_t)b * 1024) * 16;
  float h = 0.f;
  float4 cur = *(const float4*)(Uj);
  float4 nxt = *(const float4*)(Uj + 4);
  for (int s0 = 0; s0 < 1024; s0 += 4) {
    float4 fut;
    if (s0 + 8 < 1024) fut = *(const float4*)(Uj + s0 + 8);
    else { fut.x = 0.f; fut.y = 0.f; fut.z = 0.f; fut.w = 0.f; }
    float uc0 = cur.x, uc1 = cur.y, uc2 = cur.z, uc3 = cur.w;
#pragma unroll
    for (int q = 0; q < 4; q++) {
      float part = 0.f;
#pragma unroll
      for (int kk = 0; kk < 4; kk++) part = fmaf(__shfl(h, seg * 4 + kk), a[kk], part);
      float xv = part + __shfl_xor(part, 16);
      xv += __shfl_xor(xv, 32);
      float uq = (q == 0) ? uc0 : (q == 1) ? uc1 : (q == 2) ? uc2 : uc3;
      h = tanh_fast(xv) + uq;
      if (lane < 16) Hr[(size_t)(s0 + q) * 16 + j] = h;
    }
    cur = nxt; nxt = fut;
  }
}

// ---------------- comb = sum_t tw[t]*(tanh(H@C[t]) + Dv[t]*cf*gated) ----------------
__global__ __launch_bounds__(256) void comb_k(const float* Hbuf, const u16* C, const u16* Dv,
                                              const float* cf, const u16* tsl, const u16* gated,
                                              u16* comb) {
  int r = blockIdx.x, tid = threadIdx.x;
  int b = r >> 10;
  __shared__ float Hs[3][16];
  __shared__ float tw[3];
  if (tid < 48) Hs[tid >> 4][tid & 15] = Hbuf[((size_t)(tid >> 4) * 8192 + r) * 16 + (tid & 15)];
  if (tid == 0) {
    float l0 = b2f(tsl[0]), l1 = b2f(tsl[1]), l2 = b2f(tsl[2]);
    float m = fmaxf(l0, fmaxf(l1, l2));
    float e0 = __expf(l0 - m), e1 = __expf(l1 - m), e2 = __expf(l2 - m);
    float s = e0 + e1 + e2;
    tw[0] = e0 / s; tw[1] = e1 / s; tw[2] = e2 / s;
  }
  __syncthreads();
  int d0 = tid * 4;
  ushort4 gv = *(const ushort4*)(gated + (size_t)r * 1024 + d0);
  float g0 = b2f(gv.x), g1 = b2f(gv.y), g2 = b2f(gv.z), g3v = b2f(gv.w);
  float o0 = 0, o1 = 0, o2 = 0, o3 = 0;
#pragma unroll
  for (int t = 0; t < 3; t++) {
    float w = tw[t], cfv = cf[t * 8 + b];
    float dA = 0, dB = 0, dC = 0, dD = 0;
#pragma unroll
    for (int k = 0; k < 16; k++) {
      float h = Hs[t][k];
      ushort4 cv = *(const ushort4*)(C + ((size_t)t * 16 + k) * 1024 + d0);
      dA += h * b2f(cv.x); dB += h * b2f(cv.y); dC += h * b2f(cv.z); dD += h * b2f(cv.w);
    }
    float dvw = w * cfv;
    o0 += w * tanh_f(dA) + dvw * b2f(Dv[t * 1024 + d0 + 0]) * g0;
    o1 += w * tanh_f(dB) + dvw * b2f(Dv[t * 1024 + d0 + 1]) * g1;
    o2 += w * tanh_f(dC) + dvw * b2f(Dv[t * 1024 + d0 + 2]) * g2;
    o3 += w * tanh_f(dD) + dvw * b2f(Dv[t * 1024 + d0 + 3]) * g3v;
  }
  ushort4 ov;
  ov.x = f2b(o0); ov.y = f2b(o1); ov.z = f2b(o2); ov.w = f2b(o3);
  *(ushort4*)(comb + (size_t)r * 1024 + d0) = ov;
}

// ---------------- row softmax, IN PLACE ----------------
__global__ __launch_bounds__(256) void softmax_row(float* S) {
  int r = blockIdx.x, tid = threadIdx.x;
  float* row = S + (size_t)r * 1024;
  float4 v = ((const float4*)row)[tid];
  float mx = fmaxf(fmaxf(v.x, v.y), fmaxf(v.z, v.w));
  for (int o = 32; o; o >>= 1) mx = fmaxf(mx, __shfl_xor(mx, o));
  __shared__ float sm[4], ssum[4];
  int ln = tid & 63, wv = tid >> 6;
  if (!ln) sm[wv] = mx;
  __syncthreads();
  mx = fmaxf(fmaxf(sm[0], sm[1]), fmaxf(sm[2], sm[3]));
  float e0 = __expf(v.x - mx), e1 = __expf(v.y - mx), e2 = __expf(v.z - mx), e3 = __expf(v.w - mx);
  float s = e0 + e1 + e2 + e3;
  for (int o = 32; o; o >>= 1) s += __shfl_xor(s, o);
  if (!ln) ssum[wv] = s;
  __syncthreads();
  s = ssum[0] + ssum[1] + ssum[2] + ssum[3];
  float inv = 1.f / s;
  ushort4 pk;
  pk.x = f2b(e0 * inv); pk.y = f2b(e1 * inv); pk.z = f2b(e2 * inv); pk.w = f2b(e3 * inv);
  __syncthreads();
  ((ushort4*)row)[tid] = pk;
}

// ---------------- comp = mem_gated*cpf ; layernorm ----------------
__global__ __launch_bounds__(256) void ln_k(const u16* MG, const float* cpf, const u16* lng,
                                            const u16* lnb, u16* outp) {
  int r = blockIdx.x, tid = threadIdx.x;
  float cfv = cpf[r >> 10];
  ushort4 m4 = *(const ushort4*)(MG + (size_t)r * 1024 + tid * 4);
  float c0 = b2f(m4.x) * cfv, c1 = b2f(m4.y) * cfv, c2 = b2f(m4.z) * cfv, c3 = b2f(m4.w) * cfv;
  float s = c0 + c1 + c2 + c3;
  float q = c0 * c0 + c1 * c1 + c2 * c2 + c3 * c3;
  int ln = tid & 63, wv = tid >> 6;
  for (int o = 32; o; o >>= 1) { s += __shfl_xor(s, o); q += __shfl_xor(q, o); }
  __shared__ float ss[4], qq[4];
  if (!ln) { ss[wv] = s; qq[wv] = q; }
  __syncthreads();
  s = ss[0] + ss[1] + ss[2] + ss[3];
  q = qq[0] + qq[1] + qq[2] + qq[3];
  float mu = s * (1.f / 1024.f);
  float var = q * (1.f / 1024.f) - mu * mu;
  float inv = rsqrtf(fmaxf(var, 0.f) + 1e-5f);
  int d = tid * 4;
  ushort4 ov;
  ov.x = f2b((c0 - mu) * inv * b2f(lng[d + 0]) + b2f(lnb[d + 0]));
  ov.y = f2b((c1 - mu) * inv * b2f(lng[d + 1]) + b2f(lnb[d + 1]));
  ov.z = f2b((c2 - mu) * inv * b2f(lng[d + 2]) + b2f(lnb[d + 2]));
  ov.w = f2b((c3 - mu) * inv * b2f(lng[d + 3]) + b2f(lnb[d + 3]));
  *(ushort4*)(outp + (size_t)r * 1024 + d) = ov;
}

// =================================================================================
extern "C" void kernel_launch(void* const* d_in, const int* in_sizes, int n_in,
                              void* d_out, int out_size, void* d_ws, size_t ws_size,
                              hipStream_t stream) {
  (void)in_sizes; (void)n_in; (void)out_size; (void)ws_size;
  const void* x = d_in[0];
  const void* mask = d_in[1];
  const void* tsl = d_in[2];
  const void* gw1 = d_in[3];
  const void* gb1 = d_in[4];
  const void* gw2 = d_in[5];
  const void* gb2 = d_in[6];
  const void* gwts = d_in[7];
  const void* ssmA = d_in[8];
  const void* ssmBm = d_in[9];
  const void* ssmC = d_in[10];
  const void* ssmD = d_in[11];
  const void* cgw1 = d_in[12];
  const void* cgb1 = d_in[13];
  const void* cgw2 = d_in[14];
  const void* cgb2 = d_in[15];
  const void* wq = d_in[16]; const void* bq = d_in[17];
  const void* wk = d_in[18]; const void* bk = d_in[19];
  const void* wv = d_in[20]; const void* bvp = d_in[21];
  const void* wo = d_in[22]; const void* bo = d_in[23];
  const void* mgate = d_in[24];
  const void* cpw1 = d_in[25];
  const void* cpb1 = d_in[26];
  const void* cpw2 = d_in[27];
  const void* cpb2 = d_in[28];
  const void* lng = d_in[29];
  const void* lnb = d_in[30];
  const void* outw = d_in[31];
  const void* outb = d_in[32];

  // ---- workspace layout (~104 MB) ----
  char* ws = (char*)d_ws;
  const size_t MBe = 1048576;
  u16* W = (u16*)ws;                       // 6 x 2MB transposed-weight slots
  char* S1 = ws + 12582912;                // 16 MB : T1[0] -> Q -> attnT
  char* S2 = S1 + 16777216;                // 16 MB : T1[1] -> gated -> K -> normed
  char* S3 = S2 + 16777216;                // 16 MB : T1[2] -> comb
  char* SC = S3 + 16777216;                // 32 MB : xb (lo) + Gsum (hi) -> scores f32
  u16* xb = (u16*)SC;
  char* SChi = SC + 16777216;
  u8* maskb = (u8*)(SC + 33554432);        // 8 MB
  u16* SM = (u16*)(maskb + 8388608);
  char* S4 = (char*)d_out;                 // scratch: Vt -> mem_gated

  size_t off = 0;
  auto alloc = [&](size_t n) { u16* p = SM + off; off += (n + 7) & ~(size_t)7; return p; };
  u16* c_gb1 = alloc(3072);  u16* c_gb2 = alloc(3072);
  u16* c_gwts = alloc(3);    u16* c_tsl = alloc(3);
  u16* c_ssmA = alloc(768);  u16* c_ssmBm = alloc(49152);
  u16* c_ssmC = alloc(49152); u16* c_ssmD = alloc(3072);
  u16* c_cgw1 = alloc(786432); u16* c_cgb1 = alloc(768);
  u16* c_cgw2 = alloc(768);  u16* c_cgb2 = alloc(3);
  u16* c_bq = alloc(1024);   u16* c_bk = alloc(1024);
  u16* c_bv = alloc(1024);   u16* c_bo = alloc(1024);
  u16* c_mg = alloc(1024);   u16* c_cpw1 = alloc(524288);
  u16* c_cpb1 = alloc(512);  u16* c_cpw2 = alloc(512);
  u16* c_cpb2 = alloc(1);    u16* c_lng = alloc(1024);
  u16* c_lnb = alloc(1024);  u16* c_outb = alloc(1024);
  u16* BmT = alloc(49152);
  char* tail = (char*)(SM + ((off + 7) & ~(size_t)7));
  float* Ubuf = (float*)tail;       // [t][b][j][s]
  float* Hbuf = Ubuf + 393216;      // [t][r][j]
  float* Mf = Hbuf + 393216;        // col sums gated (8192)
  float* Mcf = Mf + 8192;           // col sums mem_gated (8192)
  float* accA = Mcf + 8192;         // mlp acc ctx gates: 3*8*256 = 6144
  float* accB = accA + 6144;        // mlp acc comp gate: 1*8*512 = 4096
  float* cff = accB + 4096;
  float* cpf = cff + 32;
  u32* flags = (u32*)(cpf + 8);

  // 0. detect dtypes; zero atomic accumulators (Mf..accB = 26624 floats)
  detect_k<<<1, 256, 0, stream>>>((const u32*)mgate, (const u32*)mask, flags);
  zero_f<<<104, 256, 0, stream>>>(Mf, 26624);

  // 1. convert all small arrays + x
  {
    CvtTab tb{};
    const void* srcs[NCVT] = {gb1, gb2, gwts, tsl, ssmA, ssmBm, ssmC, ssmD, cgw1, cgb1, cgw2, cgb2,
                              bq, bk, bvp, bo, mgate, cpw1, cpb1, cpw2, cpb2, lng, lnb, outb, x};
    u16* dsts[NCVT] = {c_gb1, c_gb2, c_gwts, c_tsl, c_ssmA, c_ssmBm, c_ssmC, c_ssmD, c_cgw1, c_cgb1,
                       c_cgw2, c_cgb2, c_bq, c_bk, c_bv, c_bo, c_mg, c_cpw1, c_cpb1, c_cpw2, c_cpb2,
                       c_lng, c_lnb, c_outb, xb};
    int ns[NCVT] = {3072, 3072, 3, 3, 768, 49152, 49152, 3072, 786432, 768, 768, 3,
                    1024, 1024, 1024, 1024, 1024, 524288, 512, 512, 1, 1024, 1024, 1024, 8388608};
    for (int i = 0; i < NCVT; i++) { tb.src[i] = srcs[i]; tb.dst[i] = dsts[i]; tb.n[i] = ns[i]; }
    cvt_table<<<dim3(256, NCVT), 256, 0, stream>>>(tb, flags);
  }

  // 2. mask -> u8 ; BmT
  cvt_mask<<<8192, 256, 0, stream>>>(mask, (u32*)maskb, flags);
  bmt_k<<<48, 256, 0, stream>>>(c_ssmBm, BmT);

  // 3. convert+transpose gw1 x3, gw2 x3
  {
    TPC tp{};
    for (int i = 0; i < 3; i++) { tp.src[i] = gw1; tp.soff[i] = (long)i * MBe; tp.dst[i] = W + (size_t)i * MBe; }
    for (int i = 0; i < 3; i++) { tp.src[3 + i] = gw2; tp.soff[3 + i] = (long)i * MBe; tp.dst[3 + i] = W + (size_t)(3 + i) * MBe; }
    transpose_cvt<<<dim3(16, 16, 6), dim3(64, 4), 0, stream>>>(tp, flags);
  }

  // 4. T1[i] = silu(xb @ gw1t[i] + gb1[i]), z-batched -> S1,S2,S3
  { GemmP p; p.A = xb; p.Bt = W; p.C = S1; p.sAz = 0; p.sBz = (long)MBe; p.sCzB = 16777216;
    p.lda = 1024; p.ldb = 1024; p.ldc = 1024; p.K = 1024;
    Ep e{}; e.bias = c_gb1;
    gemm_bt<0><<<dim3(8, 64, 3), 512, 0, stream>>>(p, e); }

  // 5. Gsum (+)= gweights[i]*sigmoid(T1[i] @ gw2t[i] + gb2[i]) -> SChi
  for (int i = 0; i < 3; i++) {
    GemmP p; p.A = (u16*)(S1 + (size_t)i * 16777216); p.Bt = W + (size_t)(3 + i) * MBe; p.C = SChi;
    p.sAz = 0; p.sBz = 0; p.sCzB = 0;
    p.lda = 1024; p.ldb = 1024; p.ldc = 1024; p.K = 1024;
    Ep e{}; e.bias = c_gb2 + i * 1024; e.gw = c_gwts + i; e.accum = i;
    gemm_bt<1><<<dim3(8, 64, 1), 512, 0, stream>>>(p, e);
  }

  // 6. gated = x * Gsum -> S2
  gate_combine<<<8192, 256, 0, stream>>>(xb, (u16*)SChi, (u16*)S2);

  // 7. context gates (colsum -> 2-stage MLP)
  colmean_at<<<dim3(32, 8), 256, 0, stream>>>((u16*)S2, Mf);
  mlp_s1<<<dim3(8, 3, 16), 256, 0, stream>>>(Mf, c_cgw1, accA, 256);
  mlp_s2<<<dim3(8, 3), 256, 0, stream>>>(accA, c_cgb1, c_cgw2, c_cgb2, cff, 256);

  // 8. U (transposed layout) then scan
  ssm_u_mfma<<<64, 256, 0, stream>>>((u16*)S2, BmT, cff, Ubuf);
  ssm_scan<<<dim3(8, 3), 64, 0, stream>>>(c_ssmA, Ubuf, Hbuf);

  // 9. comb -> S3
  comb_k<<<8192, 256, 0, stream>>>(Hbuf, c_ssmC, c_ssmD, cff, c_tsl, (u16*)S2, (u16*)S3);

  // 10. convert+transpose wq,wk,wv
  {
    TPC tp{};
    tp.src[0] = wq; tp.soff[0] = 0; tp.dst[0] = W;
    tp.src[1] = wk; tp.soff[1] = 0; tp.dst[1] = W + MBe;
    tp.src[2] = wv; tp.soff[2] = 0; tp.dst[2] = W + 2 * MBe;
    transpose_cvt<<<dim3(16, 16, 3), dim3(64, 4), 0, stream>>>(tp, flags);
  }

  // 11. Q->S1, K->S2, Vt->S4(d_out)
  { GemmP p; p.A = (u16*)S3; p.Bt = W; p.C = S1; p.sAz = 0; p.sBz = (long)MBe; p.sCzB = 0;
    p.lda = 1024; p.ldb = 1024; p.ldc = 1024; p.K = 1024;
    Ep e{}; e.bias = c_bq; e.bias1 = c_bk; e.bias2 = c_bv; e.cQ = S1; e.cK = S2; e.cV = S4;
    gemm_bt<2><<<dim3(8, 64, 3), 512, 0, stream>>>(p, e); }

  // 12. masked scores (f32) -> SC
  { GemmP p; p.A = (u16*)S1; p.Bt = (u16*)S2; p.C = SC; p.sAz = (long)MBe; p.sBz = (long)MBe;
    p.sCzB = 4194304; p.lda = 1024; p.ldb = 1024; p.ldc = 1024; p.K = 1024;
    Ep e{}; e.mask8 = maskb; e.scale = 0.03125f;
    gemm_bt<3><<<dim3(8, 8, 8), 512, 0, stream>>>(p, e); }

  // 13. softmax in place
  softmax_row<<<8192, 256, 0, stream>>>((float*)SC);

  // 14. attnT = (probs @ V)^T per batch -> S1
  { GemmP p; p.A = (u16*)SC; p.Bt = (u16*)S4; p.C = S1; p.sAz = 2097152; p.sBz = (long)MBe;
    p.sCzB = 2097152; p.lda = 2048; p.ldb = 1024; p.ldc = 1024; p.K = 1024;
    Ep e{};
    gemm_bt<4><<<dim3(8, 8, 8), 512, 0, stream>>>(p, e); }

  // 15. convert+transpose wo, out_w
  {
    TPC tp{};
    tp.src[0] = wo; tp.soff[0] = 0; tp.dst[0] = W;
    tp.src[1] = outw; tp.soff[1] = 0; tp.dst[1] = W + MBe;
    transpose_cvt<<<dim3(16, 16, 2), dim3(64, 4), 0, stream>>>(tp, flags);
  }

  // 16. mem_gated = (attnT @ wo + bo) * comb * mem_gate -> S4(d_out)
  { GemmP p; p.A = (u16*)S1; p.Bt = W; p.C = S4; p.sAz = 0; p.sBz = 0; p.sCzB = 0;
    p.lda = 1024; p.ldb = 1024; p.ldc = 1024; p.K = 1024;
    Ep e{}; e.bias = c_bo; e.comb = (u16*)S3; e.mgate = c_mg;
    gemm_bt<5><<<dim3(8, 64, 1), 512, 0, stream>>>(p, e); }

  // 17. compression gate (colsum -> 2-stage MLP, H=512)
  colmean_at<<<dim3(32, 8), 256, 0, stream>>>((u16*)S4, Mcf);
  mlp_s1<<<dim3(8, 1, 16), 256, 0, stream>>>(Mcf, c_cpw1, accB, 512);
  mlp_s2<<<dim3(8, 1), 256, 0, stream>>>(accB, c_cpb1, c_cpw2, c_cpb2, cpf, 512);

  // 18. scale + layernorm -> normed -> S2
  ln_k<<<8192, 256, 0, stream>>>((u16*)S4, cpf, c_lng, c_lnb, (u16*)S2);

  // 19. out = normed @ out_w + out_b -> d_out (dtype per flags)
  { GemmP p; p.A = (u16*)S2; p.Bt = W + MBe; p.C = (char*)d_out; p.sAz = 0; p.sBz = 0; p.sCzB = 0;
    p.lda = 1024; p.ldb = 1024; p.ldc = 1024; p.K = 1024;
    Ep e{}; e.bias = c_outb; e.flags = flags;
    gemm_bt<6><<<dim3(8, 64, 1), 512, 0, stream>>>(p, e); }
}